// Round 1
// baseline (1181.163 us; speedup 1.0000x reference)
//
#include <hip/hip_runtime.h>
#include <math.h>

#define B_ 4
#define N_ 8192
#define C_ 512
#define H_ 8
#define DH 64
#define G_ 64
#define M_ (B_ * N_) /* 32768 */

// ---------------------------------------------------------------------------
// K1: LayerNorm over C=512. One wave per row, 4 waves per block.
// ---------------------------------------------------------------------------
__global__ __launch_bounds__(256) void ln_kernel(
    const float* __restrict__ x, const float* __restrict__ gam,
    const float* __restrict__ bet, float* __restrict__ y) {
  int wave = threadIdx.x >> 6, lane = threadIdx.x & 63;
  int row = (blockIdx.x << 2) + wave;
  const float4* xr = (const float4*)(x + (size_t)row * C_);
  float4 v0 = xr[lane], v1 = xr[lane + 64];
  float s = v0.x + v0.y + v0.z + v0.w + v1.x + v1.y + v1.z + v1.w;
  float q = v0.x * v0.x + v0.y * v0.y + v0.z * v0.z + v0.w * v0.w +
            v1.x * v1.x + v1.y * v1.y + v1.z * v1.z + v1.w * v1.w;
#pragma unroll
  for (int off = 32; off; off >>= 1) {
    s += __shfl_xor(s, off);
    q += __shfl_xor(q, off);
  }
  float mean = s * (1.0f / C_);
  float var = q * (1.0f / C_) - mean * mean;
  float rstd = rsqrtf(var + 1e-5f);
  const float4* gr = (const float4*)gam;
  const float4* br = (const float4*)bet;
  float4 g0 = gr[lane], g1 = gr[lane + 64];
  float4 b0 = br[lane], b1 = br[lane + 64];
  float4 o0, o1;
  o0.x = (v0.x - mean) * rstd * g0.x + b0.x;
  o0.y = (v0.y - mean) * rstd * g0.y + b0.y;
  o0.z = (v0.z - mean) * rstd * g0.z + b0.z;
  o0.w = (v0.w - mean) * rstd * g0.w + b0.w;
  o1.x = (v1.x - mean) * rstd * g1.x + b1.x;
  o1.y = (v1.y - mean) * rstd * g1.y + b1.y;
  o1.z = (v1.z - mean) * rstd * g1.z + b1.z;
  o1.w = (v1.w - mean) * rstd * g1.w + b1.w;
  float4* yr = (float4*)(y + (size_t)row * C_);
  yr[lane] = o0;
  yr[lane + 64] = o1;
}

// ---------------------------------------------------------------------------
// K2/K7: fp32 GEMM  C[M,512] = A[M,512] @ W[512,512] + bias (+ resid)
// 128x128 tile, BK=8, 256 threads, 8x8 micro-tile.
// ---------------------------------------------------------------------------
template <bool RES>
__global__ __launch_bounds__(256) void gemm512(
    const float* __restrict__ A, const float* __restrict__ W,
    const float* __restrict__ bias, const float* __restrict__ resid,
    float* __restrict__ Cc) {
  __shared__ float As[8][128];  // As[k][m]
  __shared__ float Bs[8][128];  // Bs[k][n]
  int t = threadIdx.x;
  int bm = (int)blockIdx.y << 7, bn = (int)blockIdx.x << 7;
  int tx = t & 15, ty = t >> 4;
  int ar = t >> 1, ac = (t & 1) << 2;
  int brk = t >> 5, bc = (t & 31) << 2;
  float acc[8][8];
#pragma unroll
  for (int i = 0; i < 8; i++)
#pragma unroll
    for (int j = 0; j < 8; j++) acc[i][j] = 0.f;

  for (int k0 = 0; k0 < 512; k0 += 8) {
    float4 av = *(const float4*)(A + (size_t)(bm + ar) * 512 + k0 + ac);
    float4 bv = *(const float4*)(W + (size_t)(k0 + brk) * 512 + bn + bc);
    As[ac + 0][ar] = av.x;
    As[ac + 1][ar] = av.y;
    As[ac + 2][ar] = av.z;
    As[ac + 3][ar] = av.w;
    *(float4*)&Bs[brk][bc] = bv;
    __syncthreads();
#pragma unroll
    for (int kk = 0; kk < 8; kk++) {
      float4 a0 = *(const float4*)&As[kk][ty << 3];
      float4 a1 = *(const float4*)&As[kk][(ty << 3) + 4];
      float4 b0 = *(const float4*)&Bs[kk][tx << 3];
      float4 b1 = *(const float4*)&Bs[kk][(tx << 3) + 4];
      float aa[8] = {a0.x, a0.y, a0.z, a0.w, a1.x, a1.y, a1.z, a1.w};
      float bb[8] = {b0.x, b0.y, b0.z, b0.w, b1.x, b1.y, b1.z, b1.w};
#pragma unroll
      for (int i = 0; i < 8; i++)
#pragma unroll
        for (int j = 0; j < 8; j++) acc[i][j] += aa[i] * bb[j];
    }
    __syncthreads();
  }
#pragma unroll
  for (int i = 0; i < 8; i++) {
    int row = bm + (ty << 3) + i;
#pragma unroll
    for (int j4 = 0; j4 < 2; j4++) {
      int col = bn + (tx << 3) + (j4 << 2);
      float4 o;
      o.x = acc[i][(j4 << 2) + 0] + bias[col + 0];
      o.y = acc[i][(j4 << 2) + 1] + bias[col + 1];
      o.z = acc[i][(j4 << 2) + 2] + bias[col + 2];
      o.w = acc[i][(j4 << 2) + 3] + bias[col + 3];
      if (RES) {
        float4 r = *(const float4*)(resid + (size_t)row * 512 + col);
        o.x += r.x;
        o.y += r.y;
        o.z += r.z;
        o.w += r.w;
      }
      *(float4*)(Cc + (size_t)row * 512 + col) = o;
    }
  }
}

// ---------------------------------------------------------------------------
// K3: per (b,n,h): logits = x_mid[.,64] @ Wslice + bslice ; softmax(/temp)
// writes slice_w IN PLACE over x_mid (same 64-float slot). Also emits
// per-(b,h,nchunk) partial sums of slice_w over n (for slice_norm).
// One wave per (b,h,128-n-chunk). grid=512, block=256 (4 waves).
// ---------------------------------------------------------------------------
__global__ __launch_bounds__(256) void slice_kernel(
    float* __restrict__ xmid /* in: x_mid, out: slice_w */,
    const float* __restrict__ Wslice, const float* __restrict__ bslice,
    const float* __restrict__ temp, float* __restrict__ norm_part) {
  __shared__ float Ws[64 * 64];
  int t = threadIdx.x;
#pragma unroll
  for (int i = 0; i < 16; i++) Ws[t + i * 256] = Wslice[t + i * 256];
  __syncthreads();
  int wave = t >> 6, lane = t & 63;
  int blk = blockIdx.x;  // [0,512)
  int half = blk & 1;
  int nc = (blk >> 1) & 63;
  int b = blk >> 7;
  int h = half * 4 + wave;
  float invt = 1.0f / temp[h];
  float bsl = bslice[lane];
  float nacc = 0.f;
  int n0 = nc << 7;
  for (int nn = 0; nn < 128; nn++) {
    int n = n0 + nn;
    float* xp = xmid + ((((size_t)(b * N_ + n)) * H_ + h) << 6);
    float xv = xp[lane];
    float acc = bsl;
#pragma unroll 8
    for (int d = 0; d < 64; d++) acc += __shfl(xv, d) * Ws[(d << 6) + lane];
    acc *= invt;
    float m = acc;
#pragma unroll
    for (int off = 32; off; off >>= 1) m = fmaxf(m, __shfl_xor(m, off));
    float e = expf(acc - m);
    float ssum = e;
#pragma unroll
    for (int off = 32; off; off >>= 1) ssum += __shfl_xor(ssum, off);
    float w = e / ssum;
    xp[lane] = w;
    nacc += w;
  }
  norm_part[(((size_t)(b * H_ + h) << 6) + nc) * 64 + lane] = nacc;
}

// ---------------------------------------------------------------------------
// K4: pooled token partials: tok_part[b,h,c][g,d] = sum_{n in chunk c}
//     fx_mid[b,n,h,d] * slice_w[b,n,h,g].  grid=(b,h,c)=512, block=256.
// ---------------------------------------------------------------------------
__global__ __launch_bounds__(256) void pool_kernel(
    const float* __restrict__ fxmid, const float* __restrict__ sw,
    float* __restrict__ tok_part) {
  __shared__ float fx4[4][64];
  __shared__ float w4[4][64];
  int t = threadIdx.x;
  int blk = blockIdx.x;  // c:4b | h:3b | b:2b
  int c = blk & 15, h = (blk >> 4) & 7, b = blk >> 7;
  int g0 = (t >> 6) << 4, d = t & 63;
  int lr = t >> 6, lc = t & 63;
  float acc[16];
#pragma unroll
  for (int j = 0; j < 16; j++) acc[j] = 0.f;
  int n0 = c << 9;  // 512 n per chunk
  for (int nn = 0; nn < 512; nn += 4) {
    int n = n0 + nn + lr;
    size_t base = (((size_t)(b * N_ + n)) * H_ + h) << 6;
    fx4[lr][lc] = fxmid[base + lc];
    w4[lr][lc] = sw[base + lc];
    __syncthreads();
#pragma unroll
    for (int r = 0; r < 4; r++) {
      float fv = fx4[r][d];
#pragma unroll
      for (int j = 0; j < 16; j++) acc[j] += w4[r][g0 + j] * fv;
    }
    __syncthreads();
  }
  float* outp = tok_part + (((size_t)(b * H_ + h) * 16 + c) << 12);
#pragma unroll
  for (int j = 0; j < 16; j++) outp[((g0 + j) << 6) + d] = acc[j];
}

// ---------------------------------------------------------------------------
// K5: per (b,h) token pipeline: reduce partials -> normalize -> qkv ->
//     attention -> +res -> LN -> MLP(gelu) -> +res -> tokens.
// One block (256 thr) per bh. Thread owns (g=t>>2, 16 cols c0=(t&3)*16).
// ---------------------------------------------------------------------------
__device__ __forceinline__ float gelu_exact(float x) {
  return 0.5f * x * (1.0f + erff(x * 0.70710678118654752f));
}

__global__ __launch_bounds__(256) void token_kernel(
    const float* __restrict__ tok_part, const float* __restrict__ norm_part,
    const float* __restrict__ Wq, const float* __restrict__ Wk,
    const float* __restrict__ Wv, const float* __restrict__ tg,
    const float* __restrict__ tb, const float* __restrict__ Wm1,
    const float* __restrict__ bm1, const float* __restrict__ Wm2,
    const float* __restrict__ bm2, float* __restrict__ tokens) {
  __shared__ float S0[4096];  // slice_tok, later mlp hidden halves
  __shared__ float S1[4096];  // q, attn, out_tok
  __shared__ float S2[4096];  // k, v, ln-out h
  __shared__ float red[64];
  int bh = blockIdx.x, t = threadIdx.x;
  int g = t >> 2, c0 = (t & 3) << 4;
  int i0 = t << 4;

  // ---- reduce tok_part (16 chunks) and norm_part (64 chunks) ----
  float r16[16];
#pragma unroll
  for (int j = 0; j < 16; j++) r16[j] = 0.f;
  const float* tp = tok_part + ((size_t)bh << 16);
  for (int cc = 0; cc < 16; cc++) {
    const float* p = tp + (cc << 12) + i0;
#pragma unroll
    for (int j = 0; j < 16; j++) r16[j] += p[j];
  }
  if (t < 64) {
    float s = 0.f;
    const float* np = norm_part + ((size_t)bh << 12);
    for (int nc = 0; nc < 64; nc++) s += np[(nc << 6) + t];
    red[t] = s;
  }
  __syncthreads();
  float rn = 1.0f / (red[t >> 2] + 1e-5f);
#pragma unroll
  for (int j = 0; j < 16; j++) S0[i0 + j] = r16[j] * rn;  // slice_tok
  __syncthreads();

  // ---- q,k ----
  const float* s0r = &S0[g << 6];
  float q16[16], k16[16];
#pragma unroll
  for (int j = 0; j < 16; j++) {
    q16[j] = 0.f;
    k16[j] = 0.f;
  }
  for (int dd = 0; dd < 64; dd++) {
    float sv = s0r[dd];
    const float* wq = Wq + (dd << 6) + c0;
    const float* wk = Wk + (dd << 6) + c0;
#pragma unroll
    for (int j = 0; j < 16; j++) {
      q16[j] += sv * wq[j];
      k16[j] += sv * wk[j];
    }
  }
#pragma unroll
  for (int j = 0; j < 16; j++) {
    S1[(g << 6) + c0 + j] = q16[j];
    S2[(g << 6) + c0 + j] = k16[j];
  }
  __syncthreads();

  // ---- attn = softmax(q k^T / 8) ----
  float at[16];
#pragma unroll
  for (int j = 0; j < 16; j++) at[j] = 0.f;
  const float* qr = &S1[g << 6];
  for (int d = 0; d < 64; d++) {
    float qv = qr[d];
#pragma unroll
    for (int j = 0; j < 16; j++) at[j] += qv * S2[((c0 + j) << 6) + d];
  }
  float m = at[0] * 0.125f;
#pragma unroll
  for (int j = 0; j < 16; j++) {
    at[j] *= 0.125f;
    m = fmaxf(m, at[j]);
  }
  m = fmaxf(m, __shfl_xor(m, 1));
  m = fmaxf(m, __shfl_xor(m, 2));
  float ssum = 0.f;
#pragma unroll
  for (int j = 0; j < 16; j++) {
    at[j] = expf(at[j] - m);
    ssum += at[j];
  }
  ssum += __shfl_xor(ssum, 1);
  ssum += __shfl_xor(ssum, 2);
  float inv = 1.0f / ssum;
#pragma unroll
  for (int j = 0; j < 16; j++) at[j] *= inv;
  __syncthreads();  // everyone done reading q(S1), k(S2)
#pragma unroll
  for (int j = 0; j < 16; j++) S1[(g << 6) + c0 + j] = at[j];  // attn
  // ---- v ----
  float v16[16];
#pragma unroll
  for (int j = 0; j < 16; j++) v16[j] = 0.f;
  for (int dd = 0; dd < 64; dd++) {
    float sv = s0r[dd];
    const float* wv = Wv + (dd << 6) + c0;
#pragma unroll
    for (int j = 0; j < 16; j++) v16[j] += sv * wv[j];
  }
#pragma unroll
  for (int j = 0; j < 16; j++) S2[(g << 6) + c0 + j] = v16[j];
  __syncthreads();

  // ---- out_tok = attn @ v + slice_tok ----
  float o16[16];
#pragma unroll
  for (int j = 0; j < 16; j++) o16[j] = S0[(g << 6) + c0 + j];
  const float* ar = &S1[g << 6];
  for (int p = 0; p < 64; p++) {
    float av = ar[p];
#pragma unroll
    for (int j = 0; j < 16; j++) o16[j] += av * S2[(p << 6) + c0 + j];
  }
  __syncthreads();  // done reading S0,S1,S2
#pragma unroll
  for (int j = 0; j < 16; j++) S1[(g << 6) + c0 + j] = o16[j];  // out_tok
  // ---- LN(out_tok) -> S2 ----
  float sm = 0.f, sq = 0.f;
#pragma unroll
  for (int j = 0; j < 16; j++) {
    sm += o16[j];
    sq += o16[j] * o16[j];
  }
  sm += __shfl_xor(sm, 1);
  sm += __shfl_xor(sm, 2);
  sq += __shfl_xor(sq, 1);
  sq += __shfl_xor(sq, 2);
  float mean = sm * (1.0f / 64.0f);
  float var = sq * (1.0f / 64.0f) - mean * mean;
  float rstd = rsqrtf(var + 1e-5f);
#pragma unroll
  for (int j = 0; j < 16; j++)
    S2[(g << 6) + c0 + j] = (o16[j] - mean) * rstd * tg[c0 + j] + tb[c0 + j];
  __syncthreads();

  // ---- MLP: hm = gelu(h @ Wm1 + bm1) [64x128]; out = hm @ Wm2 + bm2 ----
  const float* hr = &S2[g << 6];
  float fo[16];
#pragma unroll
  for (int j = 0; j < 16; j++) fo[j] = 0.f;
  // phase A: low half e in [0,64)
  {
    float hm[16];
#pragma unroll
    for (int j = 0; j < 16; j++) hm[j] = bm1[c0 + j];
    for (int dd = 0; dd < 64; dd++) {
      float hv = hr[dd];
      const float* w = Wm1 + (dd << 7) + c0;
#pragma unroll
      for (int j = 0; j < 16; j++) hm[j] += hv * w[j];
    }
#pragma unroll
    for (int j = 0; j < 16; j++) S0[(g << 6) + c0 + j] = gelu_exact(hm[j]);
    __syncthreads();
    const float* hl = &S0[g << 6];
    for (int e = 0; e < 64; e++) {
      float hv = hl[e];
      const float* w = Wm2 + (e << 6) + c0;
#pragma unroll
      for (int j = 0; j < 16; j++) fo[j] += hv * w[j];
    }
    __syncthreads();
  }
  // phase B: high half e in [64,128)
  {
    float hm[16];
#pragma unroll
    for (int j = 0; j < 16; j++) hm[j] = bm1[64 + c0 + j];
    for (int dd = 0; dd < 64; dd++) {
      float hv = hr[dd];
      const float* w = Wm1 + (dd << 7) + 64 + c0;
#pragma unroll
      for (int j = 0; j < 16; j++) hm[j] += hv * w[j];
    }
    __syncthreads();
#pragma unroll
    for (int j = 0; j < 16; j++) S0[(g << 6) + c0 + j] = gelu_exact(hm[j]);
    __syncthreads();
    const float* hl = &S0[g << 6];
    for (int e = 0; e < 64; e++) {
      float hv = hl[e];
      const float* w = Wm2 + ((64 + e) << 6) + c0;
#pragma unroll
      for (int j = 0; j < 16; j++) fo[j] += hv * w[j];
    }
  }
  // tokens = mlp + out_tok
#pragma unroll
  for (int j = 0; j < 16; j++)
    tokens[((size_t)bh << 12) + (g << 6) + c0 + j] =
        fo[j] + bm2[c0 + j] + o16[j];
}

// ---------------------------------------------------------------------------
// K6: deslice: out_x[b,n,h,d] = sum_g tokens[b,h,g,d] * slice_w[b,n,h,g]
// grid=(b,h,64-n-chunk)=4096 blocks, 256 thr; thread=(n_local=t>>2, 16 d's).
// ---------------------------------------------------------------------------
__global__ __launch_bounds__(256) void deslice_kernel(
    const float* __restrict__ tokens, const float* __restrict__ sw,
    float* __restrict__ outx) {
  __shared__ float tok[4096];
  __shared__ float wl[64][64];
  int t = threadIdx.x;
  int blk = blockIdx.x;  // nc:7b | h:3b | b:2b
  int nc = blk & 127, h = (blk >> 7) & 7, b = blk >> 10;
  const float* tp = tokens + ((size_t)(b * H_ + h) << 12);
#pragma unroll
  for (int i = 0; i < 16; i++) tok[t + i * 256] = tp[t + i * 256];
  int n0 = nc << 6;
#pragma unroll
  for (int i = 0; i < 16; i++) {
    int idx = t + i * 256;
    int nl = idx >> 6, gg = idx & 63;
    wl[nl][gg] = sw[((((size_t)(b * N_ + n0 + nl)) * H_ + h) << 6) + gg];
  }
  __syncthreads();
  int nl = t >> 2, d0 = (t & 3) << 4;
  float acc[16];
#pragma unroll
  for (int j = 0; j < 16; j++) acc[j] = 0.f;
  for (int gidx = 0; gidx < 64; gidx++) {
    float wv = wl[nl][gidx];
    const float* tr = &tok[(gidx << 6) + d0];
#pragma unroll
    for (int j = 0; j < 16; j++) acc[j] += wv * tr[j];
  }
  float* op = outx + ((((size_t)(b * N_ + n0 + nl)) * H_ + h) << 6) + d0;
#pragma unroll
  for (int j4 = 0; j4 < 4; j4++)
    *(float4*)(op + (j4 << 2)) = make_float4(acc[j4 * 4 + 0], acc[j4 * 4 + 1],
                                             acc[j4 * 4 + 2], acc[j4 * 4 + 3]);
}

// ---------------------------------------------------------------------------
extern "C" void kernel_launch(void* const* d_in, const int* in_sizes, int n_in,
                              void* d_out, int out_size, void* d_ws,
                              size_t ws_size, hipStream_t stream) {
  const float* fx = (const float*)d_in[0];
  const float* ln1g = (const float*)d_in[1];
  const float* ln1b = (const float*)d_in[2];
  const float* Wx = (const float*)d_in[3];
  const float* bx = (const float*)d_in[4];
  const float* Wfx = (const float*)d_in[5];
  const float* bfx = (const float*)d_in[6];
  const float* Wsl = (const float*)d_in[7];
  const float* bsl = (const float*)d_in[8];
  const float* temp = (const float*)d_in[9];
  const float* Wq = (const float*)d_in[10];
  const float* Wk = (const float*)d_in[11];
  const float* Wv = (const float*)d_in[12];
  const float* Wout = (const float*)d_in[13];
  const float* bout = (const float*)d_in[14];
  const float* tlng = (const float*)d_in[15];
  const float* tlnb = (const float*)d_in[16];
  const float* Wm1 = (const float*)d_in[17];
  const float* bm1 = (const float*)d_in[18];
  const float* Wm2 = (const float*)d_in[19];
  const float* bm2 = (const float*)d_in[20];
  float* out = (float*)d_out;
  float* ws = (float*)d_ws;

  const size_t MC = (size_t)M_ * 512;
  float* fx_norm = ws;            // [M,512]
  float* buf1 = ws + MC;          // x_mid -> slice_w   [M,H,64]
  float* buf2 = ws + 2 * MC;      // fx_mid -> out_x    [M,H,64]
  float* norm_part = ws + 3 * MC;            // 32*64*64
  float* tok_part = norm_part + 32 * 64 * 64;  // 32*16*4096
  float* tokens = tok_part + 32 * 16 * 4096;   // 32*4096

  ln_kernel<<<M_ / 4, 256, 0, stream>>>(fx, ln1g, ln1b, fx_norm);
  dim3 gg(4, 256);
  gemm512<false><<<gg, 256, 0, stream>>>(fx_norm, Wx, bx, nullptr, buf1);
  gemm512<false><<<gg, 256, 0, stream>>>(fx_norm, Wfx, bfx, nullptr, buf2);
  slice_kernel<<<512, 256, 0, stream>>>(buf1, Wsl, bsl, temp, norm_part);
  pool_kernel<<<512, 256, 0, stream>>>(buf2, buf1, tok_part);
  token_kernel<<<32, 256, 0, stream>>>(tok_part, norm_part, Wq, Wk, Wv, tlng,
                                       tlnb, Wm1, bm1, Wm2, bm2, tokens);
  deslice_kernel<<<4096, 256, 0, stream>>>(tokens, buf1, buf2);
  gemm512<true><<<gg, 256, 0, stream>>>(buf2, Wout, bout, fx_norm, out);
}

// Round 2
// 363.072 us; speedup vs baseline: 3.2532x; 3.2532x over previous
//
#include <hip/hip_runtime.h>
#include <math.h>

#define B_ 4
#define N_ 8192
#define C_ 512
#define H_ 8
#define M_ (B_ * N_) /* 32768 */

typedef __attribute__((ext_vector_type(8))) short bf16x8;
typedef __attribute__((ext_vector_type(4))) float f32x4;
typedef __attribute__((ext_vector_type(8))) unsigned short u16x8;
typedef __attribute__((ext_vector_type(4))) unsigned short u16x4;

__device__ __forceinline__ float b2f(unsigned short u) {
  union { unsigned int i; float f; } v;
  v.i = ((unsigned int)u) << 16;
  return v.f;
}
__device__ __forceinline__ unsigned short f2b(float f) {
  union { float f; unsigned int i; } v;
  v.f = f;
  unsigned int r = v.i + 0x7fff + ((v.i >> 16) & 1);
  return (unsigned short)(r >> 16);
}
__device__ __forceinline__ void gl_lds16(const void* g, void* l) {
  __builtin_amdgcn_global_load_lds(
      (const __attribute__((address_space(1))) unsigned int*)g,
      (__attribute__((address_space(3))) unsigned int*)l, 16, 0, 0);
}

// ---------------------------------------------------------------------------
// K1: LayerNorm over C=512 -> bf16. One wave per row.
// ---------------------------------------------------------------------------
__global__ __launch_bounds__(256) void ln_bf16(
    const float* __restrict__ x, const float* __restrict__ gam,
    const float* __restrict__ bet, unsigned short* __restrict__ y) {
  int wave = threadIdx.x >> 6, lane = threadIdx.x & 63;
  int row = (blockIdx.x << 2) + wave;
  const float4* xr = (const float4*)(x + (size_t)row * C_);
  float4 v0 = xr[lane], v1 = xr[lane + 64];
  float s = v0.x + v0.y + v0.z + v0.w + v1.x + v1.y + v1.z + v1.w;
  float q = v0.x * v0.x + v0.y * v0.y + v0.z * v0.z + v0.w * v0.w +
            v1.x * v1.x + v1.y * v1.y + v1.z * v1.z + v1.w * v1.w;
#pragma unroll
  for (int off = 32; off; off >>= 1) {
    s += __shfl_xor(s, off);
    q += __shfl_xor(q, off);
  }
  float mean = s * (1.0f / C_);
  float var = q * (1.0f / C_) - mean * mean;
  float rstd = rsqrtf(var + 1e-5f);
  const float4* gr = (const float4*)gam;
  const float4* br = (const float4*)bet;
  float4 g0 = gr[lane], g1 = gr[lane + 64];
  float4 b0 = br[lane], b1 = br[lane + 64];
  u16x4 oa, ob;
  oa.x = f2b((v0.x - mean) * rstd * g0.x + b0.x);
  oa.y = f2b((v0.y - mean) * rstd * g0.y + b0.y);
  oa.z = f2b((v0.z - mean) * rstd * g0.z + b0.z);
  oa.w = f2b((v0.w - mean) * rstd * g0.w + b0.w);
  ob.x = f2b((v1.x - mean) * rstd * g1.x + b1.x);
  ob.y = f2b((v1.y - mean) * rstd * g1.y + b1.y);
  ob.z = f2b((v1.z - mean) * rstd * g1.z + b1.z);
  ob.w = f2b((v1.w - mean) * rstd * g1.w + b1.w);
  unsigned short* yr = y + (size_t)row * C_;
  *(u16x4*)(yr + (lane << 2)) = oa;
  *(u16x4*)(yr + 256 + (lane << 2)) = ob;
}

// ---------------------------------------------------------------------------
// K2: weight fp32 [512,512] (k-major) -> bf16 transposed Wt[n][k]
// ---------------------------------------------------------------------------
__global__ __launch_bounds__(256) void wconv_t(const float* __restrict__ W,
                                               unsigned short* __restrict__ Wt) {
  __shared__ float tile[64][65];
  int t = threadIdx.x;
  int r0 = (int)blockIdx.y << 6, c0 = (int)blockIdx.x << 6;
  int lr = t >> 4, lc = (t & 15) << 2;
#pragma unroll
  for (int p = 0; p < 4; p++) {
    float4 v = *(const float4*)(W + (size_t)(r0 + lr + p * 16) * 512 + c0 + lc);
    tile[lr + p * 16][lc + 0] = v.x;
    tile[lr + p * 16][lc + 1] = v.y;
    tile[lr + p * 16][lc + 2] = v.z;
    tile[lr + p * 16][lc + 3] = v.w;
  }
  __syncthreads();
  int on = t >> 2, ok = (t & 3) << 4;
  unsigned short tmp[16];
#pragma unroll
  for (int j = 0; j < 16; j++) tmp[j] = f2b(tile[ok + j][on]);
  unsigned short* op = Wt + (size_t)(c0 + on) * 512 + r0 + ok;
#pragma unroll
  for (int j4 = 0; j4 < 4; j4++) *(u16x4*)(op + (j4 << 2)) = *(u16x4*)(tmp + (j4 << 2));
}

// ---------------------------------------------------------------------------
// K3: precompute Wslice^T bf16 fragments: wf[(gt*2+ks)*64 + l][8]
//     element jj = Ws[ks*32 + (l>>4)*8 + jj][gt*16 + (l&15)]
// ---------------------------------------------------------------------------
__global__ __launch_bounds__(256) void wslice_prep(const float* __restrict__ Ws,
                                                   unsigned short* __restrict__ wf) {
  int t = threadIdx.x;
#pragma unroll
  for (int i = 0; i < 2; i++) {
    int idx = t + i * 256;
    int f = idx >> 6, l = idx & 63;
    int gt = f >> 1, ks = f & 1;
    int g = (gt << 4) + (l & 15);
    int d0 = (ks << 5) + ((l >> 4) << 3);
    unsigned short v[8];
#pragma unroll
    for (int jj = 0; jj < 8; jj++) v[jj] = f2b(Ws[(size_t)(d0 + jj) * 64 + g]);
    *(u16x4*)(wf + idx * 8) = *(u16x4*)v;
    *(u16x4*)(wf + idx * 8 + 4) = *(u16x4*)(v + 4);
  }
}

// ---------------------------------------------------------------------------
// K4: bf16 MFMA GEMM  C[M,512] = A[M,512] @ Wt^T + bias (+resid)
// 128x128 tile, BK=32, 4 waves (2x2 of 64x64), global_load_lds width 16.
// Grid: 1024 blocks 1-D, XCD-chunked swizzle.
// ---------------------------------------------------------------------------
template <bool OUTBF, bool RES>
__global__ __launch_bounds__(256) void gemm_bf16(
    const unsigned short* __restrict__ A, const unsigned short* __restrict__ Bt,
    const float* __restrict__ bias, const unsigned short* __restrict__ resid,
    void* __restrict__ Cout) {
  __shared__ unsigned short lds[8192];  // As[128][32] @0, Bs[128][32] @4096
  const int t = threadIdx.x;
  const int w = t >> 6, l = t & 63;
  int bid = blockIdx.x;
  int xcd = bid & 7, q = bid >> 3;
  const int bm = ((xcd << 5) + (q >> 2)) << 7;
  const int bn = (q & 3) << 7;
  const int wm = (w >> 1) << 6, wn = (w & 1) << 6;
  f32x4 acc[4][4];
#pragma unroll
  for (int mt = 0; mt < 4; mt++)
#pragma unroll
    for (int nt = 0; nt < 4; nt++) acc[mt][nt] = (f32x4){0.f, 0.f, 0.f, 0.f};

  const int srow = t >> 2;          // 0..63
  const int scol = (t & 3) << 3;    // elem offset 0,8,16,24
  const unsigned short* gA0 = A + (size_t)(bm + srow) * 512 + scol;
  const unsigned short* gA1 = A + (size_t)(bm + 64 + srow) * 512 + scol;
  const unsigned short* gB0 = Bt + (size_t)(bn + srow) * 512 + scol;
  const unsigned short* gB1 = Bt + (size_t)(bn + 64 + srow) * 512 + scol;
  const int fr = l & 15, fq = (l >> 4) << 3;

  for (int k0 = 0; k0 < 512; k0 += 32) {
    gl_lds16(gA0 + k0, lds + (w << 9));
    gl_lds16(gA1 + k0, lds + 2048 + (w << 9));
    gl_lds16(gB0 + k0, lds + 4096 + (w << 9));
    gl_lds16(gB1 + k0, lds + 6144 + (w << 9));
    __syncthreads();
    bf16x8 af[4], bfr[4];
#pragma unroll
    for (int mt = 0; mt < 4; mt++)
      af[mt] = *(const bf16x8*)&lds[(wm + mt * 16 + fr) * 32 + fq];
#pragma unroll
    for (int nt = 0; nt < 4; nt++)
      bfr[nt] = *(const bf16x8*)&lds[4096 + (wn + nt * 16 + fr) * 32 + fq];
#pragma unroll
    for (int mt = 0; mt < 4; mt++)
#pragma unroll
      for (int nt = 0; nt < 4; nt++)
        acc[mt][nt] = __builtin_amdgcn_mfma_f32_16x16x32_bf16(
            af[mt], bfr[nt], acc[mt][nt], 0, 0, 0);
    __syncthreads();
  }

  const int col0 = bn + wn + (l & 15);
  const int row0 = bm + wm + ((l >> 4) << 2);
#pragma unroll
  for (int mt = 0; mt < 4; mt++) {
#pragma unroll
    for (int j = 0; j < 4; j++) {
      int row = row0 + mt * 16 + j;
#pragma unroll
      for (int nt = 0; nt < 4; nt++) {
        int col = col0 + nt * 16;
        float v = acc[mt][nt][j] + bias[col];
        if (RES) v += b2f(resid[(size_t)row * 512 + col]);
        if (OUTBF)
          ((unsigned short*)Cout)[(size_t)row * 512 + col] = f2b(v);
        else
          ((float*)Cout)[(size_t)row * 512 + col] = v;
      }
    }
  }
}

// ---------------------------------------------------------------------------
// K5: slice softmax via MFMA. Rows = (b,n,h) flat [262144][64] bf16 in/out.
// D[g][row]: mfma(Ws^T frag, X row-frag). Per lane: one row, 16 g's.
// ---------------------------------------------------------------------------
__global__ __launch_bounds__(256) void slice_mfma(
    unsigned short* __restrict__ xw, const unsigned short* __restrict__ wf,
    const float* __restrict__ bslice, const float* __restrict__ temp) {
  __shared__ unsigned short xs[4096];  // [64 rows][64] bf16, 16B-slot XOR swizzle
  int t = threadIdx.x, w = t >> 6, l = t & 63;
  int blk = blockIdx.x;
  size_t base = (size_t)blk << 12;

  // stage X (each wave stages its own 16 rows)
  {
    int srow = t >> 2;
    const unsigned short* gp = xw + base + srow * 64 + ((t & 3) << 4);
    u16x8 a = *(const u16x8*)gp;
    u16x8 b = *(const u16x8*)(gp + 8);
    int sl0 = (t & 3) << 1, swz = srow & 7;
    *(u16x8*)&xs[srow * 64 + ((sl0 ^ swz) << 3)] = a;
    *(u16x8*)&xs[srow * 64 + (((sl0 + 1) ^ swz) << 3)] = b;
  }
  // Ws^T frags from precomputed buffer (coalesced)
  bf16x8 wsf[4][2];
#pragma unroll
  for (int gt = 0; gt < 4; gt++)
#pragma unroll
    for (int ks = 0; ks < 2; ks++)
      wsf[gt][ks] = *(const bf16x8*)(wf + (((gt << 1) + ks) * 64 + l) * 8);
  __syncthreads();

  int xr = (w << 4) + (l & 15);
  f32x4 acc[4];
#pragma unroll
  for (int gt = 0; gt < 4; gt++) acc[gt] = (f32x4){0.f, 0.f, 0.f, 0.f};
#pragma unroll
  for (int ks = 0; ks < 2; ks++) {
    int slot = (ks << 2) + (l >> 4);
    bf16x8 xf = *(const bf16x8*)&xs[xr * 64 + ((slot ^ (xr & 7)) << 3)];
#pragma unroll
    for (int gt = 0; gt < 4; gt++)
      acc[gt] = __builtin_amdgcn_mfma_f32_16x16x32_bf16(wsf[gt][ks], xf,
                                                        acc[gt], 0, 0, 0);
  }

  int gxr = (blk << 6) + xr;
  float invt = 1.0f / temp[gxr & 7];
  int qq = l >> 4;
  float lg[16];
  float mx = -1e30f;
#pragma unroll
  for (int gt = 0; gt < 4; gt++)
#pragma unroll
    for (int r = 0; r < 4; r++) {
      float v = (acc[gt][r] + bslice[(gt << 4) + (qq << 2) + r]) * invt;
      lg[(gt << 2) + r] = v;
      mx = fmaxf(mx, v);
    }
  mx = fmaxf(mx, __shfl_xor(mx, 16));
  mx = fmaxf(mx, __shfl_xor(mx, 32));
  float ssum = 0.f;
#pragma unroll
  for (int i = 0; i < 16; i++) {
    lg[i] = expf(lg[i] - mx);
    ssum += lg[i];
  }
  ssum += __shfl_xor(ssum, 16);
  ssum += __shfl_xor(ssum, 32);
  float inv = 1.0f / ssum;
  // scatter to LDS (4 consecutive g per gt), then coalesced store
  __syncthreads();  // all frag reads done before overwrite
#pragma unroll
  for (int gt = 0; gt < 4; gt++) {
    int slot = (gt << 1) + (qq >> 1);
    int off = ((slot ^ (xr & 7)) << 3) + ((qq & 1) << 2);
    u16x4 pk;
    pk.x = f2b(lg[(gt << 2) + 0] * inv);
    pk.y = f2b(lg[(gt << 2) + 1] * inv);
    pk.z = f2b(lg[(gt << 2) + 2] * inv);
    pk.w = f2b(lg[(gt << 2) + 3] * inv);
    *(u16x4*)&xs[xr * 64 + off] = pk;
  }
  __syncthreads();
  {
    int rr = (w << 4) + (l >> 2);
    int sl = (l & 3) << 1, swz = rr & 7;
    u16x8 o0 = *(const u16x8*)&xs[rr * 64 + ((sl ^ swz) << 3)];
    u16x8 o1 = *(const u16x8*)&xs[rr * 64 + (((sl + 1) ^ swz) << 3)];
    unsigned short* op = xw + base + rr * 64 + ((l & 3) << 4);
    *(u16x8*)op = o0;
    *(u16x8*)(op + 8) = o1;
  }
}

// ---------------------------------------------------------------------------
// K6: pool: tok_part[bh,c][g,d] = sum_{n in chunk} fx_mid[n][d]*w[n][g];
//     also norm_part[bh,c][g] = sum_n w[n][g].  512 blocks (b,h,c16).
// ---------------------------------------------------------------------------
__global__ __launch_bounds__(256) void pool_bf16(
    const unsigned short* __restrict__ fxmid, const unsigned short* __restrict__ sw,
    float* __restrict__ tok_part, float* __restrict__ norm_part) {
  __shared__ float fx16[16][64];
  __shared__ float w16[16][64];
  __shared__ float wred[4][64];
  int t = threadIdx.x;
  int blk = blockIdx.x;
  int c = blk & 15, h = (blk >> 4) & 7, b = blk >> 7;
  int wv = t >> 6, l = t & 63;
  int g0 = wv << 4;
  int lr = t >> 4, lc = (t & 15) << 2;
  float acc[16];
#pragma unroll
  for (int j = 0; j < 16; j++) acc[j] = 0.f;
  float wsum = 0.f;
  int n0 = c << 9;
  for (int nn = 0; nn < 512; nn += 16) {
    size_t rbase = ((size_t)(b * N_ + n0 + nn + lr) * 8 + h) << 6;
    u16x4 fv = *(const u16x4*)(fxmid + rbase + lc);
    u16x4 wq = *(const u16x4*)(sw + rbase + lc);
    __syncthreads();
    fx16[lr][lc + 0] = b2f(fv.x);
    fx16[lr][lc + 1] = b2f(fv.y);
    fx16[lr][lc + 2] = b2f(fv.z);
    fx16[lr][lc + 3] = b2f(fv.w);
    w16[lr][lc + 0] = b2f(wq.x);
    w16[lr][lc + 1] = b2f(wq.y);
    w16[lr][lc + 2] = b2f(wq.z);
    w16[lr][lc + 3] = b2f(wq.w);
    __syncthreads();
#pragma unroll
    for (int r = 0; r < 16; r++) {
      float f = fx16[r][l];
#pragma unroll
      for (int j = 0; j < 16; j++) acc[j] += w16[r][g0 + j] * f;
    }
#pragma unroll
    for (int rr = 0; rr < 4; rr++) wsum += w16[(rr << 2) + wv][l];
  }
  wred[wv][l] = wsum;
  __syncthreads();
  float* outp = tok_part + ((size_t)((b * 8 + h) * 16 + c) << 12);
#pragma unroll
  for (int j = 0; j < 16; j++) outp[((g0 + j) << 6) + l] = acc[j];
  if (t < 64) {
    float s = wred[0][t] + wred[1][t] + wred[2][t] + wred[3][t];
    norm_part[((size_t)((b * 8 + h) * 16 + c) << 6) + t] = s;
  }
}

// ---------------------------------------------------------------------------
// K7: per (b,h) token pipeline (fp32, one block per bh).
// ---------------------------------------------------------------------------
__device__ __forceinline__ float gelu_exact(float x) {
  return 0.5f * x * (1.0f + erff(x * 0.70710678118654752f));
}

__global__ __launch_bounds__(256) void token_kernel(
    const float* __restrict__ tok_part, const float* __restrict__ norm_part,
    const float* __restrict__ Wq, const float* __restrict__ Wk,
    const float* __restrict__ Wv, const float* __restrict__ tg,
    const float* __restrict__ tb, const float* __restrict__ Wm1,
    const float* __restrict__ bm1, const float* __restrict__ Wm2,
    const float* __restrict__ bm2, float* __restrict__ tokens) {
  __shared__ float S0[4096];
  __shared__ float S1[4096];
  __shared__ float S2[4096];
  __shared__ float red[64];
  int bh = blockIdx.x, t = threadIdx.x;
  int g = t >> 2, c0 = (t & 3) << 4;
  int i0 = t << 4;

  float r16[16];
#pragma unroll
  for (int j = 0; j < 16; j++) r16[j] = 0.f;
  const float* tp = tok_part + ((size_t)bh << 16);
  for (int cc = 0; cc < 16; cc++) {
    const float* p = tp + (cc << 12) + i0;
#pragma unroll
    for (int j = 0; j < 16; j++) r16[j] += p[j];
  }
  if (t < 64) {
    float s = 0.f;
    const float* np = norm_part + ((size_t)bh << 10);
    for (int nc = 0; nc < 16; nc++) s += np[(nc << 6) + t];
    red[t] = s;
  }
  __syncthreads();
  float rn = 1.0f / (red[t >> 2] + 1e-5f);
#pragma unroll
  for (int j = 0; j < 16; j++) S0[i0 + j] = r16[j] * rn;
  __syncthreads();

  const float* s0r = &S0[g << 6];
  float q16[16], k16[16];
#pragma unroll
  for (int j = 0; j < 16; j++) {
    q16[j] = 0.f;
    k16[j] = 0.f;
  }
  for (int dd = 0; dd < 64; dd++) {
    float sv = s0r[dd];
    const float* wq = Wq + (dd << 6) + c0;
    const float* wk = Wk + (dd << 6) + c0;
#pragma unroll
    for (int j = 0; j < 16; j++) {
      q16[j] += sv * wq[j];
      k16[j] += sv * wk[j];
    }
  }
#pragma unroll
  for (int j = 0; j < 16; j++) {
    S1[(g << 6) + c0 + j] = q16[j];
    S2[(g << 6) + c0 + j] = k16[j];
  }
  __syncthreads();

  float at[16];
#pragma unroll
  for (int j = 0; j < 16; j++) at[j] = 0.f;
  const float* qr = &S1[g << 6];
  for (int d = 0; d < 64; d++) {
    float qv = qr[d];
#pragma unroll
    for (int j = 0; j < 16; j++) at[j] += qv * S2[((c0 + j) << 6) + d];
  }
  float m = at[0] * 0.125f;
#pragma unroll
  for (int j = 0; j < 16; j++) {
    at[j] *= 0.125f;
    m = fmaxf(m, at[j]);
  }
  m = fmaxf(m, __shfl_xor(m, 1));
  m = fmaxf(m, __shfl_xor(m, 2));
  float ssum = 0.f;
#pragma unroll
  for (int j = 0; j < 16; j++) {
    at[j] = expf(at[j] - m);
    ssum += at[j];
  }
  ssum += __shfl_xor(ssum, 1);
  ssum += __shfl_xor(ssum, 2);
  float inv = 1.0f / ssum;
#pragma unroll
  for (int j = 0; j < 16; j++) at[j] *= inv;
  __syncthreads();
#pragma unroll
  for (int j = 0; j < 16; j++) S1[(g << 6) + c0 + j] = at[j];
  float v16[16];
#pragma unroll
  for (int j = 0; j < 16; j++) v16[j] = 0.f;
  for (int dd = 0; dd < 64; dd++) {
    float sv = s0r[dd];
    const float* wv = Wv + (dd << 6) + c0;
#pragma unroll
    for (int j = 0; j < 16; j++) v16[j] += sv * wv[j];
  }
#pragma unroll
  for (int j = 0; j < 16; j++) S2[(g << 6) + c0 + j] = v16[j];
  __syncthreads();

  float o16[16];
#pragma unroll
  for (int j = 0; j < 16; j++) o16[j] = S0[(g << 6) + c0 + j];
  const float* ar = &S1[g << 6];
  for (int p = 0; p < 64; p++) {
    float av = ar[p];
#pragma unroll
    for (int j = 0; j < 16; j++) o16[j] += av * S2[(p << 6) + c0 + j];
  }
  __syncthreads();
#pragma unroll
  for (int j = 0; j < 16; j++) S1[(g << 6) + c0 + j] = o16[j];
  float sm = 0.f, sq = 0.f;
#pragma unroll
  for (int j = 0; j < 16; j++) {
    sm += o16[j];
    sq += o16[j] * o16[j];
  }
  sm += __shfl_xor(sm, 1);
  sm += __shfl_xor(sm, 2);
  sq += __shfl_xor(sq, 1);
  sq += __shfl_xor(sq, 2);
  float mean = sm * (1.0f / 64.0f);
  float var = sq * (1.0f / 64.0f) - mean * mean;
  float rstd = rsqrtf(var + 1e-5f);
#pragma unroll
  for (int j = 0; j < 16; j++)
    S2[(g << 6) + c0 + j] = (o16[j] - mean) * rstd * tg[c0 + j] + tb[c0 + j];
  __syncthreads();

  const float* hr = &S2[g << 6];
  float fo[16];
#pragma unroll
  for (int j = 0; j < 16; j++) fo[j] = 0.f;
  {
    float hm[16];
#pragma unroll
    for (int j = 0; j < 16; j++) hm[j] = bm1[c0 + j];
    for (int dd = 0; dd < 64; dd++) {
      float hv = hr[dd];
      const float* wv = Wm1 + (dd << 7) + c0;
#pragma unroll
      for (int j = 0; j < 16; j++) hm[j] += hv * wv[j];
    }
#pragma unroll
    for (int j = 0; j < 16; j++) S0[(g << 6) + c0 + j] = gelu_exact(hm[j]);
    __syncthreads();
    const float* hl = &S0[g << 6];
    for (int e = 0; e < 64; e++) {
      float hv = hl[e];
      const float* wv = Wm2 + (e << 6) + c0;
#pragma unroll
      for (int j = 0; j < 16; j++) fo[j] += hv * wv[j];
    }
    __syncthreads();
  }
  {
    float hm[16];
#pragma unroll
    for (int j = 0; j < 16; j++) hm[j] = bm1[64 + c0 + j];
    for (int dd = 0; dd < 64; dd++) {
      float hv = hr[dd];
      const float* wv = Wm1 + (dd << 7) + 64 + c0;
#pragma unroll
      for (int j = 0; j < 16; j++) hm[j] += hv * wv[j];
    }
    __syncthreads();
#pragma unroll
    for (int j = 0; j < 16; j++) S0[(g << 6) + c0 + j] = gelu_exact(hm[j]);
    __syncthreads();
    const float* hl = &S0[g << 6];
    for (int e = 0; e < 64; e++) {
      float hv = hl[e];
      const float* wv = Wm2 + ((64 + e) << 6) + c0;
#pragma unroll
      for (int j = 0; j < 16; j++) fo[j] += hv * wv[j];
    }
  }
#pragma unroll
  for (int j = 0; j < 16; j++)
    tokens[((size_t)bh << 12) + (g << 6) + c0 + j] =
        fo[j] + bm2[c0 + j] + o16[j];
}

// ---------------------------------------------------------------------------
// K8: deslice: out_x[n][d] = sum_g tokens[g][d]*w[n][g], bf16 in/out.
// ---------------------------------------------------------------------------
__global__ __launch_bounds__(256) void deslice_bf16(
    const float* __restrict__ tokens, const unsigned short* __restrict__ sw,
    unsigned short* __restrict__ outx) {
  __shared__ float tok[4096];
  __shared__ float wl[64][65];
  int t = threadIdx.x;
  int blk = blockIdx.x;  // nc:7 | h:3 | b:2
  int nc = blk & 127, h = (blk >> 7) & 7, b = blk >> 10;
  const float* tp = tokens + ((size_t)(b * 8 + h) << 12);
#pragma unroll
  for (int i = 0; i < 16; i++) tok[t + i * 256] = tp[t + i * 256];
  int n0 = nc << 6;
  {
    int r = t >> 2, cs = (t & 3) << 4;
    size_t rb = ((size_t)(b * N_ + n0 + r) * 8 + h) << 6;
    u16x8 a = *(const u16x8*)(sw + rb + cs);
    u16x8 bq = *(const u16x8*)(sw + rb + cs + 8);
#pragma unroll
    for (int i = 0; i < 8; i++) {
      wl[r][cs + i] = b2f(a[i]);
      wl[r][cs + 8 + i] = b2f(bq[i]);
    }
  }
  __syncthreads();
  int nl = t >> 2, d0 = (t & 3) << 4;
  float acc[16];
#pragma unroll
  for (int j = 0; j < 16; j++) acc[j] = 0.f;
  for (int gi = 0; gi < 64; gi++) {
    float wv = wl[nl][gi];
    const float* tr = &tok[(gi << 6) + d0];
#pragma unroll
    for (int j = 0; j < 16; j++) acc[j] += wv * tr[j];
  }
  unsigned short ov[16];
#pragma unroll
  for (int j = 0; j < 16; j++) ov[j] = f2b(acc[j]);
  unsigned short* op = outx + (((size_t)(b * N_ + n0 + nl) * 8 + h) << 6) + d0;
  *(u16x8*)op = *(u16x8*)ov;
  *(u16x8*)(op + 8) = *(u16x8*)(ov + 8);
}

// ---------------------------------------------------------------------------
extern "C" void kernel_launch(void* const* d_in, const int* in_sizes, int n_in,
                              void* d_out, int out_size, void* d_ws,
                              size_t ws_size, hipStream_t stream) {
  const float* fx = (const float*)d_in[0];
  const float* ln1g = (const float*)d_in[1];
  const float* ln1b = (const float*)d_in[2];
  const float* Wx = (const float*)d_in[3];
  const float* bx = (const float*)d_in[4];
  const float* Wfx = (const float*)d_in[5];
  const float* bfx = (const float*)d_in[6];
  const float* Wsl = (const float*)d_in[7];
  const float* bsl = (const float*)d_in[8];
  const float* temp = (const float*)d_in[9];
  const float* Wq = (const float*)d_in[10];
  const float* Wk = (const float*)d_in[11];
  const float* Wv = (const float*)d_in[12];
  const float* Wout = (const float*)d_in[13];
  const float* bout = (const float*)d_in[14];
  const float* tlng = (const float*)d_in[15];
  const float* tlnb = (const float*)d_in[16];
  const float* Wm1 = (const float*)d_in[17];
  const float* bm1 = (const float*)d_in[18];
  const float* Wm2 = (const float*)d_in[19];
  const float* bm2 = (const float*)d_in[20];
  float* out = (float*)d_out;

  char* p = (char*)d_ws;
  const size_t MC2 = (size_t)M_ * 512 * 2;
  unsigned short* fxn = (unsigned short*)p;  p += MC2;
  unsigned short* buf1 = (unsigned short*)p; p += MC2;
  unsigned short* buf2 = (unsigned short*)p; p += MC2;
  unsigned short* WtX = (unsigned short*)p;  p += 512 * 512 * 2;
  unsigned short* WtF = (unsigned short*)p;  p += 512 * 512 * 2;
  unsigned short* WtO = (unsigned short*)p;  p += 512 * 512 * 2;
  unsigned short* wsf = (unsigned short*)p;  p += 8192;
  float* tok_part = (float*)p;  p += (size_t)32 * 16 * 4096 * 4;
  float* norm_part = (float*)p; p += (size_t)32 * 16 * 64 * 4;
  float* tokens = (float*)p;    p += (size_t)32 * 4096 * 4;

  ln_bf16<<<M_ / 4, 256, 0, stream>>>(fx, ln1g, ln1b, fxn);
  dim3 wg(8, 8);
  wconv_t<<<wg, 256, 0, stream>>>(Wx, WtX);
  wconv_t<<<wg, 256, 0, stream>>>(Wfx, WtF);
  wconv_t<<<wg, 256, 0, stream>>>(Wout, WtO);
  wslice_prep<<<1, 256, 0, stream>>>(Wsl, wsf);
  gemm_bf16<true, false><<<1024, 256, 0, stream>>>(fxn, WtX, bx, nullptr, buf1);
  gemm_bf16<true, false><<<1024, 256, 0, stream>>>(fxn, WtF, bfx, nullptr, buf2);
  slice_mfma<<<4096, 256, 0, stream>>>(buf1, wsf, bsl, temp);
  pool_bf16<<<512, 256, 0, stream>>>(buf2, buf1, tok_part, norm_part);
  token_kernel<<<32, 256, 0, stream>>>(tok_part, norm_part, Wq, Wk, Wv, tlng,
                                       tlnb, Wm1, bm1, Wm2, bm2, tokens);
  deslice_bf16<<<4096, 256, 0, stream>>>(tokens, buf1, buf2);
  gemm_bf16<false, true><<<1024, 256, 0, stream>>>(buf2, WtO, bout, fxn, out);
}

// Round 3
// 252.842 us; speedup vs baseline: 4.6715x; 1.4360x over previous
//
#include <hip/hip_runtime.h>
#include <math.h>

#define B_ 4
#define N_ 8192
#define C_ 512
#define H_ 8
#define M_ (B_ * N_) /* 32768 */

typedef __attribute__((ext_vector_type(8))) short bf16x8;
typedef __attribute__((ext_vector_type(4))) float f32x4;
typedef __attribute__((ext_vector_type(8))) unsigned short u16x8;
typedef __attribute__((ext_vector_type(4))) unsigned short u16x4;

__device__ __forceinline__ float b2f(unsigned short u) {
  union { unsigned int i; float f; } v;
  v.i = ((unsigned int)u) << 16;
  return v.f;
}
__device__ __forceinline__ unsigned short f2b(float f) {
  union { float f; unsigned int i; } v;
  v.f = f;
  unsigned int r = v.i + 0x7fff + ((v.i >> 16) & 1);
  return (unsigned short)(r >> 16);
}
__device__ __forceinline__ void gl_lds16(const void* g, void* l) {
  __builtin_amdgcn_global_load_lds(
      (const __attribute__((address_space(1))) unsigned int*)g,
      (__attribute__((address_space(3))) unsigned int*)l, 16, 0, 0);
}

// ---------------------------------------------------------------------------
// K1: LayerNorm over C=512 -> bf16. One wave per row.
// ---------------------------------------------------------------------------
__global__ __launch_bounds__(256) void ln_bf16(
    const float* __restrict__ x, const float* __restrict__ gam,
    const float* __restrict__ bet, unsigned short* __restrict__ y) {
  int wave = threadIdx.x >> 6, lane = threadIdx.x & 63;
  int row = (blockIdx.x << 2) + wave;
  const float4* xr = (const float4*)(x + (size_t)row * C_);
  float4 v0 = xr[lane], v1 = xr[lane + 64];
  float s = v0.x + v0.y + v0.z + v0.w + v1.x + v1.y + v1.z + v1.w;
  float q = v0.x * v0.x + v0.y * v0.y + v0.z * v0.z + v0.w * v0.w +
            v1.x * v1.x + v1.y * v1.y + v1.z * v1.z + v1.w * v1.w;
#pragma unroll
  for (int off = 32; off; off >>= 1) {
    s += __shfl_xor(s, off);
    q += __shfl_xor(q, off);
  }
  float mean = s * (1.0f / C_);
  float var = q * (1.0f / C_) - mean * mean;
  float rstd = rsqrtf(var + 1e-5f);
  const float4* gr = (const float4*)gam;
  const float4* br = (const float4*)bet;
  float4 g0 = gr[lane], g1 = gr[lane + 64];
  float4 b0 = br[lane], b1 = br[lane + 64];
  u16x4 oa, ob;
  oa.x = f2b((v0.x - mean) * rstd * g0.x + b0.x);
  oa.y = f2b((v0.y - mean) * rstd * g0.y + b0.y);
  oa.z = f2b((v0.z - mean) * rstd * g0.z + b0.z);
  oa.w = f2b((v0.w - mean) * rstd * g0.w + b0.w);
  ob.x = f2b((v1.x - mean) * rstd * g1.x + b1.x);
  ob.y = f2b((v1.y - mean) * rstd * g1.y + b1.y);
  ob.z = f2b((v1.z - mean) * rstd * g1.z + b1.z);
  ob.w = f2b((v1.w - mean) * rstd * g1.w + b1.w);
  unsigned short* yr = y + (size_t)row * C_;
  *(u16x4*)(yr + (lane << 2)) = oa;
  *(u16x4*)(yr + 256 + (lane << 2)) = ob;
}

// ---------------------------------------------------------------------------
// K2: weight fp32 [512,512] (k-major) -> bf16 transposed Wt[n][k]
// ---------------------------------------------------------------------------
__global__ __launch_bounds__(256) void wconv_t(const float* __restrict__ W,
                                               unsigned short* __restrict__ Wt) {
  __shared__ float tile[64][65];
  int t = threadIdx.x;
  int r0 = (int)blockIdx.y << 6, c0 = (int)blockIdx.x << 6;
  int lr = t >> 4, lc = (t & 15) << 2;
#pragma unroll
  for (int p = 0; p < 4; p++) {
    float4 v = *(const float4*)(W + (size_t)(r0 + lr + p * 16) * 512 + c0 + lc);
    tile[lr + p * 16][lc + 0] = v.x;
    tile[lr + p * 16][lc + 1] = v.y;
    tile[lr + p * 16][lc + 2] = v.z;
    tile[lr + p * 16][lc + 3] = v.w;
  }
  __syncthreads();
  int on = t >> 2, ok = (t & 3) << 4;
  unsigned short tmp[16];
#pragma unroll
  for (int j = 0; j < 16; j++) tmp[j] = f2b(tile[ok + j][on]);
  unsigned short* op = Wt + (size_t)(c0 + on) * 512 + r0 + ok;
#pragma unroll
  for (int j4 = 0; j4 < 4; j4++) *(u16x4*)(op + (j4 << 2)) = *(u16x4*)(tmp + (j4 << 2));
}

// ---------------------------------------------------------------------------
// K3: precompute Wslice^T bf16 fragments
// ---------------------------------------------------------------------------
__global__ __launch_bounds__(256) void wslice_prep(const float* __restrict__ Ws,
                                                   unsigned short* __restrict__ wf) {
  int t = threadIdx.x;
#pragma unroll
  for (int i = 0; i < 2; i++) {
    int idx = t + i * 256;
    int f = idx >> 6, l = idx & 63;
    int gt = f >> 1, ks = f & 1;
    int g = (gt << 4) + (l & 15);
    int d0 = (ks << 5) + ((l >> 4) << 3);
    unsigned short v[8];
#pragma unroll
    for (int jj = 0; jj < 8; jj++) v[jj] = f2b(Ws[(size_t)(d0 + jj) * 64 + g]);
    *(u16x4*)(wf + idx * 8) = *(u16x4*)v;
    *(u16x4*)(wf + idx * 8 + 4) = *(u16x4*)(v + 4);
  }
}

// ---------------------------------------------------------------------------
// K3b: precompute B-operand fragments for token pipeline weights.
// frag(fid): lane l elem j = W[k = ks*32+(l>>4)*8+j][n = ct*16+(l&15)]
//  fid 0..7  : Wq  (ct=fid>>1, ks=fid&1)   [64x64]
//  fid 8..15 : Wk
//  fid 16..23: Wv
//  fid 24..39: Wm1 (et=(fid-24)>>1, ks=&1) [64x128]
//  fid 40..55: Wm2 (ct=(fid-40)>>2, ks=&3) [128x64]
// ---------------------------------------------------------------------------
__global__ __launch_bounds__(256) void wfrag_prep(
    const float* __restrict__ Wq, const float* __restrict__ Wk,
    const float* __restrict__ Wv, const float* __restrict__ Wm1,
    const float* __restrict__ Wm2, unsigned short* __restrict__ wfr) {
  int t = threadIdx.x;
  for (int task = t; task < 56 * 64; task += 256) {
    int fid = task >> 6, l = task & 63;
    const float* W;
    int stride, ct, ks;
    if (fid < 24) {
      W = (fid < 8) ? Wq : (fid < 16) ? Wk : Wv;
      int e = fid & 7;
      ct = e >> 1;
      ks = e & 1;
      stride = 64;
    } else if (fid < 40) {
      W = Wm1;
      int e = fid - 24;
      ct = e >> 1;
      ks = e & 1;
      stride = 128;
    } else {
      W = Wm2;
      int e = fid - 40;
      ct = e >> 2;
      ks = e & 3;
      stride = 64;
    }
    int d0 = (ks << 5) + ((l >> 4) << 3);
    int c = (ct << 4) + (l & 15);
    unsigned short v[8];
#pragma unroll
    for (int j = 0; j < 8; j++) v[j] = f2b(W[(size_t)(d0 + j) * stride + c]);
    *(u16x4*)(wfr + task * 8) = *(u16x4*)v;
    *(u16x4*)(wfr + task * 8 + 4) = *(u16x4*)(v + 4);
  }
}

// ---------------------------------------------------------------------------
// K4: bf16 MFMA GEMM  C[M,512] = A[M,512] @ Wt^T + bias (+resid)
// ---------------------------------------------------------------------------
template <bool OUTBF, bool RES>
__global__ __launch_bounds__(256) void gemm_bf16(
    const unsigned short* __restrict__ A, const unsigned short* __restrict__ Bt,
    const float* __restrict__ bias, const unsigned short* __restrict__ resid,
    void* __restrict__ Cout) {
  __shared__ unsigned short lds[8192];
  const int t = threadIdx.x;
  const int w = t >> 6, l = t & 63;
  int bid = blockIdx.x;
  int xcd = bid & 7, q = bid >> 3;
  const int bm = ((xcd << 5) + (q >> 2)) << 7;
  const int bn = (q & 3) << 7;
  const int wm = (w >> 1) << 6, wn = (w & 1) << 6;
  f32x4 acc[4][4];
#pragma unroll
  for (int mt = 0; mt < 4; mt++)
#pragma unroll
    for (int nt = 0; nt < 4; nt++) acc[mt][nt] = (f32x4){0.f, 0.f, 0.f, 0.f};

  const int srow = t >> 2;
  const int scol = (t & 3) << 3;
  const unsigned short* gA0 = A + (size_t)(bm + srow) * 512 + scol;
  const unsigned short* gA1 = A + (size_t)(bm + 64 + srow) * 512 + scol;
  const unsigned short* gB0 = Bt + (size_t)(bn + srow) * 512 + scol;
  const unsigned short* gB1 = Bt + (size_t)(bn + 64 + srow) * 512 + scol;
  const int fr = l & 15, fq = (l >> 4) << 3;

  for (int k0 = 0; k0 < 512; k0 += 32) {
    gl_lds16(gA0 + k0, lds + (w << 9));
    gl_lds16(gA1 + k0, lds + 2048 + (w << 9));
    gl_lds16(gB0 + k0, lds + 4096 + (w << 9));
    gl_lds16(gB1 + k0, lds + 6144 + (w << 9));
    __syncthreads();
    bf16x8 af[4], bfr[4];
#pragma unroll
    for (int mt = 0; mt < 4; mt++)
      af[mt] = *(const bf16x8*)&lds[(wm + mt * 16 + fr) * 32 + fq];
#pragma unroll
    for (int nt = 0; nt < 4; nt++)
      bfr[nt] = *(const bf16x8*)&lds[4096 + (wn + nt * 16 + fr) * 32 + fq];
#pragma unroll
    for (int mt = 0; mt < 4; mt++)
#pragma unroll
      for (int nt = 0; nt < 4; nt++)
        acc[mt][nt] = __builtin_amdgcn_mfma_f32_16x16x32_bf16(
            af[mt], bfr[nt], acc[mt][nt], 0, 0, 0);
    __syncthreads();
  }

  const int col0 = bn + wn + (l & 15);
  const int row0 = bm + wm + ((l >> 4) << 2);
#pragma unroll
  for (int mt = 0; mt < 4; mt++) {
#pragma unroll
    for (int j = 0; j < 4; j++) {
      int row = row0 + mt * 16 + j;
#pragma unroll
      for (int nt = 0; nt < 4; nt++) {
        int col = col0 + nt * 16;
        float v = acc[mt][nt][j] + bias[col];
        if (RES) v += b2f(resid[(size_t)row * 512 + col]);
        if (OUTBF)
          ((unsigned short*)Cout)[(size_t)row * 512 + col] = f2b(v);
        else
          ((float*)Cout)[(size_t)row * 512 + col] = v;
      }
    }
  }
}

// ---------------------------------------------------------------------------
// K5: slice softmax via MFMA (unchanged from round 2).
// ---------------------------------------------------------------------------
__global__ __launch_bounds__(256) void slice_mfma(
    unsigned short* __restrict__ xw, const unsigned short* __restrict__ wf,
    const float* __restrict__ bslice, const float* __restrict__ temp) {
  __shared__ unsigned short xs[4096];
  int t = threadIdx.x, w = t >> 6, l = t & 63;
  int blk = blockIdx.x;
  size_t base = (size_t)blk << 12;
  {
    int srow = t >> 2;
    const unsigned short* gp = xw + base + srow * 64 + ((t & 3) << 4);
    u16x8 a = *(const u16x8*)gp;
    u16x8 b = *(const u16x8*)(gp + 8);
    int sl0 = (t & 3) << 1, swz = srow & 7;
    *(u16x8*)&xs[srow * 64 + ((sl0 ^ swz) << 3)] = a;
    *(u16x8*)&xs[srow * 64 + (((sl0 + 1) ^ swz) << 3)] = b;
  }
  bf16x8 wsf[4][2];
#pragma unroll
  for (int gt = 0; gt < 4; gt++)
#pragma unroll
    for (int ks = 0; ks < 2; ks++)
      wsf[gt][ks] = *(const bf16x8*)(wf + (((gt << 1) + ks) * 64 + l) * 8);
  __syncthreads();

  int xr = (w << 4) + (l & 15);
  f32x4 acc[4];
#pragma unroll
  for (int gt = 0; gt < 4; gt++) acc[gt] = (f32x4){0.f, 0.f, 0.f, 0.f};
#pragma unroll
  for (int ks = 0; ks < 2; ks++) {
    int slot = (ks << 2) + (l >> 4);
    bf16x8 xf = *(const bf16x8*)&xs[xr * 64 + ((slot ^ (xr & 7)) << 3)];
#pragma unroll
    for (int gt = 0; gt < 4; gt++)
      acc[gt] = __builtin_amdgcn_mfma_f32_16x16x32_bf16(wsf[gt][ks], xf,
                                                        acc[gt], 0, 0, 0);
  }

  int gxr = (blk << 6) + xr;
  float invt = 1.0f / temp[gxr & 7];
  int qq = l >> 4;
  float lg[16];
  float mx = -1e30f;
#pragma unroll
  for (int gt = 0; gt < 4; gt++)
#pragma unroll
    for (int r = 0; r < 4; r++) {
      float v = (acc[gt][r] + bslice[(gt << 4) + (qq << 2) + r]) * invt;
      lg[(gt << 2) + r] = v;
      mx = fmaxf(mx, v);
    }
  mx = fmaxf(mx, __shfl_xor(mx, 16));
  mx = fmaxf(mx, __shfl_xor(mx, 32));
  float ssum = 0.f;
#pragma unroll
  for (int i = 0; i < 16; i++) {
    lg[i] = expf(lg[i] - mx);
    ssum += lg[i];
  }
  ssum += __shfl_xor(ssum, 16);
  ssum += __shfl_xor(ssum, 32);
  float inv = 1.0f / ssum;
  __syncthreads();
#pragma unroll
  for (int gt = 0; gt < 4; gt++) {
    int slot = (gt << 1) + (qq >> 1);
    int off = ((slot ^ (xr & 7)) << 3) + ((qq & 1) << 2);
    u16x4 pk;
    pk.x = f2b(lg[(gt << 2) + 0] * inv);
    pk.y = f2b(lg[(gt << 2) + 1] * inv);
    pk.z = f2b(lg[(gt << 2) + 2] * inv);
    pk.w = f2b(lg[(gt << 2) + 3] * inv);
    *(u16x4*)&xs[xr * 64 + off] = pk;
  }
  __syncthreads();
  {
    int rr = (w << 4) + (l >> 2);
    int sl = (l & 3) << 1, swz = rr & 7;
    u16x8 o0 = *(const u16x8*)&xs[rr * 64 + ((sl ^ swz) << 3)];
    u16x8 o1 = *(const u16x8*)&xs[rr * 64 + (((sl + 1) ^ swz) << 3)];
    unsigned short* op = xw + base + rr * 64 + ((l & 3) << 4);
    *(u16x8*)op = o0;
    *(u16x8*)(op + 8) = o1;
  }
}

// ---------------------------------------------------------------------------
// K6: pool (unchanged from round 2).
// ---------------------------------------------------------------------------
__global__ __launch_bounds__(256) void pool_bf16(
    const unsigned short* __restrict__ fxmid, const unsigned short* __restrict__ sw,
    float* __restrict__ tok_part, float* __restrict__ norm_part) {
  __shared__ float fx16[16][64];
  __shared__ float w16[16][64];
  __shared__ float wred[4][64];
  int t = threadIdx.x;
  int blk = blockIdx.x;
  int c = blk & 15, h = (blk >> 4) & 7, b = blk >> 7;
  int wv = t >> 6, l = t & 63;
  int g0 = wv << 4;
  int lr = t >> 4, lc = (t & 15) << 2;
  float acc[16];
#pragma unroll
  for (int j = 0; j < 16; j++) acc[j] = 0.f;
  float wsum = 0.f;
  int n0 = c << 9;
  for (int nn = 0; nn < 512; nn += 16) {
    size_t rbase = ((size_t)(b * N_ + n0 + nn + lr) * 8 + h) << 6;
    u16x4 fv = *(const u16x4*)(fxmid + rbase + lc);
    u16x4 wq = *(const u16x4*)(sw + rbase + lc);
    __syncthreads();
    fx16[lr][lc + 0] = b2f(fv.x);
    fx16[lr][lc + 1] = b2f(fv.y);
    fx16[lr][lc + 2] = b2f(fv.z);
    fx16[lr][lc + 3] = b2f(fv.w);
    w16[lr][lc + 0] = b2f(wq.x);
    w16[lr][lc + 1] = b2f(wq.y);
    w16[lr][lc + 2] = b2f(wq.z);
    w16[lr][lc + 3] = b2f(wq.w);
    __syncthreads();
#pragma unroll
    for (int r = 0; r < 16; r++) {
      float f = fx16[r][l];
#pragma unroll
      for (int j = 0; j < 16; j++) acc[j] += w16[r][g0 + j] * f;
    }
#pragma unroll
    for (int rr = 0; rr < 4; rr++) wsum += w16[(rr << 2) + wv][l];
  }
  wred[wv][l] = wsum;
  __syncthreads();
  float* outp = tok_part + ((size_t)((b * 8 + h) * 16 + c) << 12);
#pragma unroll
  for (int j = 0; j < 16; j++) outp[((g0 + j) << 6) + l] = acc[j];
  if (t < 64) {
    float s = wred[0][t] + wred[1][t] + wred[2][t] + wred[3][t];
    norm_part[((size_t)((b * 8 + h) * 16 + c) << 6) + t] = s;
  }
}

// ---------------------------------------------------------------------------
// K6b: reduce tok_part chunks + norm_part -> normalized slice_tok fp32.
// 128 blocks (bh*4 + quarter), 256 threads, 4 floats each.
// ---------------------------------------------------------------------------
__global__ __launch_bounds__(256) void tok_reduce(
    const float* __restrict__ tok_part, const float* __restrict__ norm_part,
    float* __restrict__ stG) {
  int blk = blockIdx.x;
  int bh = blk >> 2, qq = blk & 3;
  int t = threadIdx.x;
  int e = (qq << 10) + (t << 2);
  int g = e >> 6;
  float s = 0.f;
  const float* np = norm_part + ((size_t)bh << 10);
#pragma unroll
  for (int c = 0; c < 16; c++) s += np[(c << 6) + g];
  float4 acc = make_float4(0.f, 0.f, 0.f, 0.f);
  const float* tp = tok_part + ((size_t)bh << 16) + e;
#pragma unroll
  for (int c = 0; c < 16; c++) {
    float4 v = *(const float4*)(tp + (c << 12));
    acc.x += v.x;
    acc.y += v.y;
    acc.z += v.z;
    acc.w += v.w;
  }
  float inv = 1.0f / (s + 1e-5f);
  acc.x *= inv;
  acc.y *= inv;
  acc.z *= inv;
  acc.w *= inv;
  *(float4*)(stG + ((size_t)bh << 12) + e) = acc;
}

// ---------------------------------------------------------------------------
// K7: token pipeline via MFMA. One block per bh (32 blocks, 4 waves).
// LDS matrices padded to 72 bf16/row (144B = odd*16B -> banks spread).
// Aliasing across barriered phases: stb->P, st32->hm, qld->h.
// ---------------------------------------------------------------------------
__device__ __forceinline__ float gelu_exact(float x) {
  return 0.5f * x * (1.0f + erff(x * 0.70710678118654752f));
}

__global__ __launch_bounds__(256) void token_mfma(
    const float* __restrict__ stG, const unsigned short* __restrict__ wfr,
    const float* __restrict__ tg, const float* __restrict__ tb,
    const float* __restrict__ bm1, const float* __restrict__ bm2,
    float* __restrict__ tokens) {
  __shared__ __align__(16) char smem[54272];
  unsigned short* stb = (unsigned short*)smem;            // [64][72]; later P
  float* st32 = (float*)(smem + 9216);                    // [64][68]
  unsigned short* hmld = (unsigned short*)(smem + 9216);  // [64][136] (alias)
  unsigned short* qld = (unsigned short*)(smem + 26624);  // [64][72]; later h
  unsigned short* kld = (unsigned short*)(smem + 35840);  // [64][72]
  unsigned short* vtl = (unsigned short*)(smem + 45056);  // [64][72] v^T

  int bh = blockIdx.x, t = threadIdx.x, w = t >> 6, l = t & 63;
  const int fr = l & 15, fq = l >> 4;

  // ---- stage slice_tok: fp32 copy + bf16 copy ----
  {
    int r = t >> 2, c0 = (t & 3) << 4;
    const float* gp = stG + ((size_t)bh << 12) + r * 64 + c0;
    float4 a = *(const float4*)gp;
    float4 b = *(const float4*)(gp + 4);
    float4 c = *(const float4*)(gp + 8);
    float4 d = *(const float4*)(gp + 12);
    *(float4*)&st32[r * 68 + c0] = a;
    *(float4*)&st32[r * 68 + c0 + 4] = b;
    *(float4*)&st32[r * 68 + c0 + 8] = c;
    *(float4*)&st32[r * 68 + c0 + 12] = d;
    unsigned short tv[16];
    tv[0] = f2b(a.x); tv[1] = f2b(a.y); tv[2] = f2b(a.z); tv[3] = f2b(a.w);
    tv[4] = f2b(b.x); tv[5] = f2b(b.y); tv[6] = f2b(b.z); tv[7] = f2b(b.w);
    tv[8] = f2b(c.x); tv[9] = f2b(c.y); tv[10] = f2b(c.z); tv[11] = f2b(c.w);
    tv[12] = f2b(d.x); tv[13] = f2b(d.y); tv[14] = f2b(d.z); tv[15] = f2b(d.w);
    *(u16x8*)&stb[r * 72 + c0] = *(u16x8*)tv;
    *(u16x8*)&stb[r * 72 + c0 + 8] = *(u16x8*)(tv + 8);
  }
  __syncthreads();

  const int orow = (w << 4) + (fq << 2);  // output row base for D-layout

  // ---- QKV (wave w computes token stripe w*16..w*16+15) ----
  {
    bf16x8 af[2];
#pragma unroll
    for (int ks = 0; ks < 2; ks++)
      af[ks] = *(const bf16x8*)&stb[((w << 4) + fr) * 72 + (ks << 5) + (fq << 3)];
    f32x4 aq[4], ak[4], av[4];
#pragma unroll
    for (int ct = 0; ct < 4; ct++) {
      aq[ct] = (f32x4){0.f, 0.f, 0.f, 0.f};
      ak[ct] = (f32x4){0.f, 0.f, 0.f, 0.f};
      av[ct] = (f32x4){0.f, 0.f, 0.f, 0.f};
    }
#pragma unroll
    for (int ct = 0; ct < 4; ct++)
#pragma unroll
      for (int ks = 0; ks < 2; ks++) {
        bf16x8 bq = *(const bf16x8*)&wfr[(((ct << 1) + ks) * 64 + l) * 8];
        aq[ct] = __builtin_amdgcn_mfma_f32_16x16x32_bf16(af[ks], bq, aq[ct], 0, 0, 0);
      }
#pragma unroll
    for (int ct = 0; ct < 4; ct++)
#pragma unroll
      for (int ks = 0; ks < 2; ks++) {
        bf16x8 bk = *(const bf16x8*)&wfr[((8 + (ct << 1) + ks) * 64 + l) * 8];
        ak[ct] = __builtin_amdgcn_mfma_f32_16x16x32_bf16(af[ks], bk, ak[ct], 0, 0, 0);
      }
#pragma unroll
    for (int ct = 0; ct < 4; ct++)
#pragma unroll
      for (int ks = 0; ks < 2; ks++) {
        bf16x8 bv = *(const bf16x8*)&wfr[((16 + (ct << 1) + ks) * 64 + l) * 8];
        av[ct] = __builtin_amdgcn_mfma_f32_16x16x32_bf16(af[ks], bv, av[ct], 0, 0, 0);
      }
#pragma unroll
    for (int ct = 0; ct < 4; ct++) {
#pragma unroll
      for (int rr = 0; rr < 4; rr++) {
        qld[(orow + rr) * 72 + (ct << 4) + fr] = f2b(aq[ct][rr]);
        kld[(orow + rr) * 72 + (ct << 4) + fr] = f2b(ak[ct][rr]);
      }
      u16x4 vp;
      vp.x = f2b(av[ct][0]);
      vp.y = f2b(av[ct][1]);
      vp.z = f2b(av[ct][2]);
      vp.w = f2b(av[ct][3]);
      *(u16x4*)&vtl[((ct << 4) + fr) * 72 + orow] = vp;
    }
  }
  __syncthreads();

  // ---- S = q @ k^T * 0.125, softmax rows, P -> stb ----
  {
    bf16x8 aq[2];
#pragma unroll
    for (int ks = 0; ks < 2; ks++)
      aq[ks] = *(const bf16x8*)&qld[((w << 4) + fr) * 72 + (ks << 5) + (fq << 3)];
    f32x4 accs[4];
#pragma unroll
    for (int nt = 0; nt < 4; nt++) accs[nt] = (f32x4){0.f, 0.f, 0.f, 0.f};
#pragma unroll
    for (int nt = 0; nt < 4; nt++)
#pragma unroll
      for (int ks = 0; ks < 2; ks++) {
        bf16x8 bk = *(const bf16x8*)&kld[((nt << 4) + fr) * 72 + (ks << 5) + (fq << 3)];
        accs[nt] = __builtin_amdgcn_mfma_f32_16x16x32_bf16(aq[ks], bk, accs[nt], 0, 0, 0);
      }
#pragma unroll
    for (int rr = 0; rr < 4; rr++) {
      float v0 = accs[0][rr] * 0.125f, v1 = accs[1][rr] * 0.125f;
      float v2 = accs[2][rr] * 0.125f, v3 = accs[3][rr] * 0.125f;
      float mx = fmaxf(fmaxf(v0, v1), fmaxf(v2, v3));
      mx = fmaxf(mx, __shfl_xor(mx, 1));
      mx = fmaxf(mx, __shfl_xor(mx, 2));
      mx = fmaxf(mx, __shfl_xor(mx, 4));
      mx = fmaxf(mx, __shfl_xor(mx, 8));
      float e0 = expf(v0 - mx), e1 = expf(v1 - mx);
      float e2 = expf(v2 - mx), e3 = expf(v3 - mx);
      float ss = e0 + e1 + e2 + e3;
      ss += __shfl_xor(ss, 1);
      ss += __shfl_xor(ss, 2);
      ss += __shfl_xor(ss, 4);
      ss += __shfl_xor(ss, 8);
      float inv = 1.0f / ss;
      stb[(orow + rr) * 72 + 0 * 16 + fr] = f2b(e0 * inv);
      stb[(orow + rr) * 72 + 1 * 16 + fr] = f2b(e1 * inv);
      stb[(orow + rr) * 72 + 2 * 16 + fr] = f2b(e2 * inv);
      stb[(orow + rr) * 72 + 3 * 16 + fr] = f2b(e3 * inv);
    }
  }
  __syncthreads();

  // ---- out_tok = P @ v + slice_tok; LN -> h (qld) ----
  float o16[4][4];
  {
    bf16x8 ap[2];
#pragma unroll
    for (int ks = 0; ks < 2; ks++)
      ap[ks] = *(const bf16x8*)&stb[((w << 4) + fr) * 72 + (ks << 5) + (fq << 3)];
    f32x4 acco[4];
#pragma unroll
    for (int ct = 0; ct < 4; ct++) acco[ct] = (f32x4){0.f, 0.f, 0.f, 0.f};
#pragma unroll
    for (int ct = 0; ct < 4; ct++)
#pragma unroll
      for (int ks = 0; ks < 2; ks++) {
        bf16x8 bv = *(const bf16x8*)&vtl[((ct << 4) + fr) * 72 + (ks << 5) + (fq << 3)];
        acco[ct] = __builtin_amdgcn_mfma_f32_16x16x32_bf16(ap[ks], bv, acco[ct], 0, 0, 0);
      }
    float tgv[4], tbv[4];
#pragma unroll
    for (int ct = 0; ct < 4; ct++) {
      tgv[ct] = tg[(ct << 4) + fr];
      tbv[ct] = tb[(ct << 4) + fr];
    }
#pragma unroll
    for (int ct = 0; ct < 4; ct++)
#pragma unroll
      for (int rr = 0; rr < 4; rr++)
        o16[ct][rr] = acco[ct][rr] + st32[(orow + rr) * 68 + (ct << 4) + fr];
#pragma unroll
    for (int rr = 0; rr < 4; rr++) {
      float sm = o16[0][rr] + o16[1][rr] + o16[2][rr] + o16[3][rr];
      float sq = o16[0][rr] * o16[0][rr] + o16[1][rr] * o16[1][rr] +
                 o16[2][rr] * o16[2][rr] + o16[3][rr] * o16[3][rr];
      sm += __shfl_xor(sm, 1);
      sm += __shfl_xor(sm, 2);
      sm += __shfl_xor(sm, 4);
      sm += __shfl_xor(sm, 8);
      sq += __shfl_xor(sq, 1);
      sq += __shfl_xor(sq, 2);
      sq += __shfl_xor(sq, 4);
      sq += __shfl_xor(sq, 8);
      float mean = sm * (1.0f / 64.0f);
      float var = sq * (1.0f / 64.0f) - mean * mean;
      float rstd = rsqrtf(var + 1e-5f);
#pragma unroll
      for (int ct = 0; ct < 4; ct++) {
        float hv = (o16[ct][rr] - mean) * rstd * tgv[ct] + tbv[ct];
        qld[(orow + rr) * 72 + (ct << 4) + fr] = f2b(hv);
      }
    }
  }
  __syncthreads();

  // ---- MLP1: hm = gelu(h @ Wm1 + bm1) -> hmld [64][136] ----
  {
    bf16x8 ah[2];
#pragma unroll
    for (int ks = 0; ks < 2; ks++)
      ah[ks] = *(const bf16x8*)&qld[((w << 4) + fr) * 72 + (ks << 5) + (fq << 3)];
    f32x4 accm[8];
#pragma unroll
    for (int et = 0; et < 8; et++) accm[et] = (f32x4){0.f, 0.f, 0.f, 0.f};
#pragma unroll
    for (int et = 0; et < 8; et++)
#pragma unroll
      for (int ks = 0; ks < 2; ks++) {
        bf16x8 bm = *(const bf16x8*)&wfr[((24 + (et << 1) + ks) * 64 + l) * 8];
        accm[et] = __builtin_amdgcn_mfma_f32_16x16x32_bf16(ah[ks], bm, accm[et], 0, 0, 0);
      }
#pragma unroll
    for (int et = 0; et < 8; et++) {
      float bv = bm1[(et << 4) + fr];
#pragma unroll
      for (int rr = 0; rr < 4; rr++) {
        float x = accm[et][rr] + bv;
        hmld[(orow + rr) * 136 + (et << 4) + fr] = f2b(gelu_exact(x));
      }
    }
  }
  __syncthreads();

  // ---- MLP2: tokens = hm @ Wm2 + bm2 + out_tok ----
  {
    bf16x8 ahm[4];
#pragma unroll
    for (int ks = 0; ks < 4; ks++)
      ahm[ks] = *(const bf16x8*)&hmld[((w << 4) + fr) * 136 + (ks << 5) + (fq << 3)];
    f32x4 acc2[4];
#pragma unroll
    for (int ct = 0; ct < 4; ct++) acc2[ct] = (f32x4){0.f, 0.f, 0.f, 0.f};
#pragma unroll
    for (int ct = 0; ct < 4; ct++)
#pragma unroll
      for (int ks = 0; ks < 4; ks++) {
        bf16x8 bw = *(const bf16x8*)&wfr[((40 + (ct << 2) + ks) * 64 + l) * 8];
        acc2[ct] = __builtin_amdgcn_mfma_f32_16x16x32_bf16(ahm[ks], bw, acc2[ct], 0, 0, 0);
      }
    float* tout = tokens + ((size_t)bh << 12);
#pragma unroll
    for (int ct = 0; ct < 4; ct++) {
      float bv = bm2[(ct << 4) + fr];
#pragma unroll
      for (int rr = 0; rr < 4; rr++)
        tout[(orow + rr) * 64 + (ct << 4) + fr] = acc2[ct][rr] + bv + o16[ct][rr];
    }
  }
}

// ---------------------------------------------------------------------------
// K8: deslice (unchanged from round 2).
// ---------------------------------------------------------------------------
__global__ __launch_bounds__(256) void deslice_bf16(
    const float* __restrict__ tokens, const unsigned short* __restrict__ sw,
    unsigned short* __restrict__ outx) {
  __shared__ float tok[4096];
  __shared__ float wl[64][65];
  int t = threadIdx.x;
  int blk = blockIdx.x;
  int nc = blk & 127, h = (blk >> 7) & 7, b = blk >> 10;
  const float* tp = tokens + ((size_t)(b * 8 + h) << 12);
#pragma unroll
  for (int i = 0; i < 16; i++) tok[t + i * 256] = tp[t + i * 256];
  int n0 = nc << 6;
  {
    int r = t >> 2, cs = (t & 3) << 4;
    size_t rb = ((size_t)(b * N_ + n0 + r) * 8 + h) << 6;
    u16x8 a = *(const u16x8*)(sw + rb + cs);
    u16x8 bq = *(const u16x8*)(sw + rb + cs + 8);
#pragma unroll
    for (int i = 0; i < 8; i++) {
      wl[r][cs + i] = b2f(a[i]);
      wl[r][cs + 8 + i] = b2f(bq[i]);
    }
  }
  __syncthreads();
  int nl = t >> 2, d0 = (t & 3) << 4;
  float acc[16];
#pragma unroll
  for (int j = 0; j < 16; j++) acc[j] = 0.f;
  for (int gi = 0; gi < 64; gi++) {
    float wv = wl[nl][gi];
    const float* tr = &tok[(gi << 6) + d0];
#pragma unroll
    for (int j = 0; j < 16; j++) acc[j] += wv * tr[j];
  }
  unsigned short ov[16];
#pragma unroll
  for (int j = 0; j < 16; j++) ov[j] = f2b(acc[j]);
  unsigned short* op = outx + (((size_t)(b * N_ + n0 + nl) * 8 + h) << 6) + d0;
  *(u16x8*)op = *(u16x8*)ov;
  *(u16x8*)(op + 8) = *(u16x8*)(ov + 8);
}

// ---------------------------------------------------------------------------
extern "C" void kernel_launch(void* const* d_in, const int* in_sizes, int n_in,
                              void* d_out, int out_size, void* d_ws,
                              size_t ws_size, hipStream_t stream) {
  const float* fx = (const float*)d_in[0];
  const float* ln1g = (const float*)d_in[1];
  const float* ln1b = (const float*)d_in[2];
  const float* Wx = (const float*)d_in[3];
  const float* bx = (const float*)d_in[4];
  const float* Wfx = (const float*)d_in[5];
  const float* bfx = (const float*)d_in[6];
  const float* Wsl = (const float*)d_in[7];
  const float* bsl = (const float*)d_in[8];
  const float* temp = (const float*)d_in[9];
  const float* Wq = (const float*)d_in[10];
  const float* Wk = (const float*)d_in[11];
  const float* Wv = (const float*)d_in[12];
  const float* Wout = (const float*)d_in[13];
  const float* bout = (const float*)d_in[14];
  const float* tlng = (const float*)d_in[15];
  const float* tlnb = (const float*)d_in[16];
  const float* Wm1 = (const float*)d_in[17];
  const float* bm1 = (const float*)d_in[18];
  const float* Wm2 = (const float*)d_in[19];
  const float* bm2 = (const float*)d_in[20];
  float* out = (float*)d_out;

  char* p = (char*)d_ws;
  const size_t MC2 = (size_t)M_ * 512 * 2;
  unsigned short* fxn = (unsigned short*)p;  p += MC2;
  unsigned short* buf1 = (unsigned short*)p; p += MC2;
  unsigned short* buf2 = (unsigned short*)p; p += MC2;
  unsigned short* WtX = (unsigned short*)p;  p += 512 * 512 * 2;
  unsigned short* WtF = (unsigned short*)p;  p += 512 * 512 * 2;
  unsigned short* WtO = (unsigned short*)p;  p += 512 * 512 * 2;
  unsigned short* wsf = (unsigned short*)p;  p += 8192;
  unsigned short* wfr = (unsigned short*)p;  p += 56 * 512 * 2;
  float* tok_part = (float*)p;  p += (size_t)32 * 16 * 4096 * 4;
  float* norm_part = (float*)p; p += (size_t)32 * 16 * 64 * 4;
  float* tokens = (float*)p;    p += (size_t)32 * 4096 * 4;
  float* stG = (float*)p;       p += (size_t)32 * 4096 * 4;

  ln_bf16<<<M_ / 4, 256, 0, stream>>>(fx, ln1g, ln1b, fxn);
  dim3 wg(8, 8);
  wconv_t<<<wg, 256, 0, stream>>>(Wx, WtX);
  wconv_t<<<wg, 256, 0, stream>>>(Wfx, WtF);
  wconv_t<<<wg, 256, 0, stream>>>(Wout, WtO);
  wslice_prep<<<1, 256, 0, stream>>>(Wsl, wsf);
  wfrag_prep<<<1, 256, 0, stream>>>(Wq, Wk, Wv, Wm1, Wm2, wfr);
  gemm_bf16<true, false><<<1024, 256, 0, stream>>>(fxn, WtX, bx, nullptr, buf1);
  gemm_bf16<true, false><<<1024, 256, 0, stream>>>(fxn, WtF, bfx, nullptr, buf2);
  slice_mfma<<<4096, 256, 0, stream>>>(buf1, wsf, bsl, temp);
  pool_bf16<<<512, 256, 0, stream>>>(buf2, buf1, tok_part, norm_part);
  tok_reduce<<<128, 256, 0, stream>>>(tok_part, norm_part, stG);
  token_mfma<<<32, 256, 0, stream>>>(stG, wfr, tlng, tlnb, bm1, bm2, tokens);
  deslice_bf16<<<4096, 256, 0, stream>>>(tokens, buf1, buf2);
  gemm_bf16<false, true><<<1024, 256, 0, stream>>>(buf2, WtO, bout, fxn, out);
}

// Round 4
// 212.760 us; speedup vs baseline: 5.5516x; 1.1884x over previous
//
#include <hip/hip_runtime.h>
#include <math.h>

#define B_ 4
#define N_ 8192
#define C_ 512
#define H_ 8
#define M_ (B_ * N_) /* 32768 */

typedef __attribute__((ext_vector_type(8))) short bf16x8;
typedef __attribute__((ext_vector_type(4))) float f32x4;
typedef __attribute__((ext_vector_type(8))) unsigned short u16x8;
typedef __attribute__((ext_vector_type(4))) unsigned short u16x4;

__device__ __forceinline__ float b2f(unsigned short u) {
  union { unsigned int i; float f; } v;
  v.i = ((unsigned int)u) << 16;
  return v.f;
}
__device__ __forceinline__ unsigned short f2b(float f) {
  union { float f; unsigned int i; } v;
  v.f = f;
  unsigned int r = v.i + 0x7fff + ((v.i >> 16) & 1);
  return (unsigned short)(r >> 16);
}
__device__ __forceinline__ void gl_lds16(const void* g, void* l) {
  __builtin_amdgcn_global_load_lds(
      (const __attribute__((address_space(1))) unsigned int*)g,
      (__attribute__((address_space(3))) unsigned int*)l, 16, 0, 0);
}

// ---------------------------------------------------------------------------
// K1: LayerNorm over C=512 -> bf16. One wave per row.
// ---------------------------------------------------------------------------
__global__ __launch_bounds__(256) void ln_bf16(
    const float* __restrict__ x, const float* __restrict__ gam,
    const float* __restrict__ bet, unsigned short* __restrict__ y) {
  int wave = threadIdx.x >> 6, lane = threadIdx.x & 63;
  int row = (blockIdx.x << 2) + wave;
  const float4* xr = (const float4*)(x + (size_t)row * C_);
  float4 v0 = xr[lane], v1 = xr[lane + 64];
  float s = v0.x + v0.y + v0.z + v0.w + v1.x + v1.y + v1.z + v1.w;
  float q = v0.x * v0.x + v0.y * v0.y + v0.z * v0.z + v0.w * v0.w +
            v1.x * v1.x + v1.y * v1.y + v1.z * v1.z + v1.w * v1.w;
#pragma unroll
  for (int off = 32; off; off >>= 1) {
    s += __shfl_xor(s, off);
    q += __shfl_xor(q, off);
  }
  float mean = s * (1.0f / C_);
  float var = q * (1.0f / C_) - mean * mean;
  float rstd = rsqrtf(var + 1e-5f);
  const float4* gr = (const float4*)gam;
  const float4* br = (const float4*)bet;
  float4 g0 = gr[lane], g1 = gr[lane + 64];
  float4 b0 = br[lane], b1 = br[lane + 64];
  u16x4 oa, ob;
  oa.x = f2b((v0.x - mean) * rstd * g0.x + b0.x);
  oa.y = f2b((v0.y - mean) * rstd * g0.y + b0.y);
  oa.z = f2b((v0.z - mean) * rstd * g0.z + b0.z);
  oa.w = f2b((v0.w - mean) * rstd * g0.w + b0.w);
  ob.x = f2b((v1.x - mean) * rstd * g1.x + b1.x);
  ob.y = f2b((v1.y - mean) * rstd * g1.y + b1.y);
  ob.z = f2b((v1.z - mean) * rstd * g1.z + b1.z);
  ob.w = f2b((v1.w - mean) * rstd * g1.w + b1.w);
  unsigned short* yr = y + (size_t)row * C_;
  *(u16x4*)(yr + (lane << 2)) = oa;
  *(u16x4*)(yr + 256 + (lane << 2)) = ob;
}

// ---------------------------------------------------------------------------
// K2: weight fp32 [512,512] (k-major) -> bf16 transposed Wt[n][k]
// ---------------------------------------------------------------------------
__global__ __launch_bounds__(256) void wconv_t(const float* __restrict__ W,
                                               unsigned short* __restrict__ Wt) {
  __shared__ float tile[64][65];
  int t = threadIdx.x;
  int r0 = (int)blockIdx.y << 6, c0 = (int)blockIdx.x << 6;
  int lr = t >> 4, lc = (t & 15) << 2;
#pragma unroll
  for (int p = 0; p < 4; p++) {
    float4 v = *(const float4*)(W + (size_t)(r0 + lr + p * 16) * 512 + c0 + lc);
    tile[lr + p * 16][lc + 0] = v.x;
    tile[lr + p * 16][lc + 1] = v.y;
    tile[lr + p * 16][lc + 2] = v.z;
    tile[lr + p * 16][lc + 3] = v.w;
  }
  __syncthreads();
  int on = t >> 2, ok = (t & 3) << 4;
  unsigned short tmp[16];
#pragma unroll
  for (int j = 0; j < 16; j++) tmp[j] = f2b(tile[ok + j][on]);
  unsigned short* op = Wt + (size_t)(c0 + on) * 512 + r0 + ok;
#pragma unroll
  for (int j4 = 0; j4 < 4; j4++) *(u16x4*)(op + (j4 << 2)) = *(u16x4*)(tmp + (j4 << 2));
}

// ---------------------------------------------------------------------------
// K3: precompute Wslice^T bf16 fragments
// ---------------------------------------------------------------------------
__global__ __launch_bounds__(256) void wslice_prep(const float* __restrict__ Ws,
                                                   unsigned short* __restrict__ wf) {
  int t = threadIdx.x;
#pragma unroll
  for (int i = 0; i < 2; i++) {
    int idx = t + i * 256;
    int f = idx >> 6, l = idx & 63;
    int gt = f >> 1, ks = f & 1;
    int g = (gt << 4) + (l & 15);
    int d0 = (ks << 5) + ((l >> 4) << 3);
    unsigned short v[8];
#pragma unroll
    for (int jj = 0; jj < 8; jj++) v[jj] = f2b(Ws[(size_t)(d0 + jj) * 64 + g]);
    *(u16x4*)(wf + idx * 8) = *(u16x4*)v;
    *(u16x4*)(wf + idx * 8 + 4) = *(u16x4*)(v + 4);
  }
}

// ---------------------------------------------------------------------------
// K3b: precompute B-operand fragments for token pipeline weights.
// ---------------------------------------------------------------------------
__global__ __launch_bounds__(256) void wfrag_prep(
    const float* __restrict__ Wq, const float* __restrict__ Wk,
    const float* __restrict__ Wv, const float* __restrict__ Wm1,
    const float* __restrict__ Wm2, unsigned short* __restrict__ wfr) {
  int t = threadIdx.x;
  for (int task = t; task < 56 * 64; task += 256) {
    int fid = task >> 6, l = task & 63;
    const float* W;
    int stride, ct, ks;
    if (fid < 24) {
      W = (fid < 8) ? Wq : (fid < 16) ? Wk : Wv;
      int e = fid & 7;
      ct = e >> 1;
      ks = e & 1;
      stride = 64;
    } else if (fid < 40) {
      W = Wm1;
      int e = fid - 24;
      ct = e >> 1;
      ks = e & 1;
      stride = 128;
    } else {
      W = Wm2;
      int e = fid - 40;
      ct = e >> 2;
      ks = e & 3;
      stride = 64;
    }
    int d0 = (ks << 5) + ((l >> 4) << 3);
    int c = (ct << 4) + (l & 15);
    unsigned short v[8];
#pragma unroll
    for (int j = 0; j < 8; j++) v[j] = f2b(W[(size_t)(d0 + j) * stride + c]);
    *(u16x4*)(wfr + task * 8) = *(u16x4*)v;
    *(u16x4*)(wfr + task * 8 + 4) = *(u16x4*)(v + 4);
  }
}

// ---------------------------------------------------------------------------
// K4: bf16 MFMA GEMM  D[m,col] = A[m,:] . Bt[col,:] + bias (+resid)
// A rows: M-dim; Bt rows: col-dim; both stride 512 (K=512).
// DEC=0: 256 m-tiles x 4 n-tiles. DEC=1: 4 m-tiles x 256 n-tiles.
// ---------------------------------------------------------------------------
template <int DEC, bool BIASROW, bool OUTBF, bool RES>
__global__ __launch_bounds__(256) void gemm_bf16(
    const unsigned short* __restrict__ A, const unsigned short* __restrict__ Bt,
    const float* __restrict__ bias, const unsigned short* __restrict__ resid,
    void* __restrict__ Cout, size_t ldC) {
  __shared__ unsigned short lds[8192];
  const int t = threadIdx.x;
  const int w = t >> 6, l = t & 63;
  int bid = blockIdx.x;
  int xcd = bid & 7, q = bid >> 3;
  int bm, bn;
  if (DEC == 0) {
    bm = ((xcd << 5) + (q >> 2)) << 7;
    bn = (q & 3) << 7;
  } else {
    bn = ((xcd << 5) + (q >> 2)) << 7;
    bm = (q & 3) << 7;
  }
  const int wm = (w >> 1) << 6, wn = (w & 1) << 6;
  f32x4 acc[4][4];
#pragma unroll
  for (int mt = 0; mt < 4; mt++)
#pragma unroll
    for (int nt = 0; nt < 4; nt++) acc[mt][nt] = (f32x4){0.f, 0.f, 0.f, 0.f};

  const int srow = t >> 2;
  const int scol = (t & 3) << 3;
  const unsigned short* gA0 = A + (size_t)(bm + srow) * 512 + scol;
  const unsigned short* gA1 = A + (size_t)(bm + 64 + srow) * 512 + scol;
  const unsigned short* gB0 = Bt + (size_t)(bn + srow) * 512 + scol;
  const unsigned short* gB1 = Bt + (size_t)(bn + 64 + srow) * 512 + scol;
  const int fr = l & 15, fq = (l >> 4) << 3;

  for (int k0 = 0; k0 < 512; k0 += 32) {
    gl_lds16(gA0 + k0, lds + (w << 9));
    gl_lds16(gA1 + k0, lds + 2048 + (w << 9));
    gl_lds16(gB0 + k0, lds + 4096 + (w << 9));
    gl_lds16(gB1 + k0, lds + 6144 + (w << 9));
    __syncthreads();
    bf16x8 af[4], bfr[4];
#pragma unroll
    for (int mt = 0; mt < 4; mt++)
      af[mt] = *(const bf16x8*)&lds[(wm + mt * 16 + fr) * 32 + fq];
#pragma unroll
    for (int nt = 0; nt < 4; nt++)
      bfr[nt] = *(const bf16x8*)&lds[4096 + (wn + nt * 16 + fr) * 32 + fq];
#pragma unroll
    for (int mt = 0; mt < 4; mt++)
#pragma unroll
      for (int nt = 0; nt < 4; nt++)
        acc[mt][nt] = __builtin_amdgcn_mfma_f32_16x16x32_bf16(
            af[mt], bfr[nt], acc[mt][nt], 0, 0, 0);
    __syncthreads();
  }

  const int col0 = bn + wn + (l & 15);
  const int row0 = bm + wm + ((l >> 4) << 2);
#pragma unroll
  for (int mt = 0; mt < 4; mt++) {
#pragma unroll
    for (int j = 0; j < 4; j++) {
      int row = row0 + mt * 16 + j;
#pragma unroll
      for (int nt = 0; nt < 4; nt++) {
        int col = col0 + nt * 16;
        float v = acc[mt][nt][j] + (BIASROW ? bias[row] : bias[col]);
        if (RES) v += b2f(resid[(size_t)row * ldC + col]);
        if (OUTBF)
          ((unsigned short*)Cout)[(size_t)row * ldC + col] = f2b(v);
        else
          ((float*)Cout)[(size_t)row * ldC + col] = v;
      }
    }
  }
}

// ---------------------------------------------------------------------------
// K5: slice softmax via MFMA (unchanged).
// ---------------------------------------------------------------------------
__global__ __launch_bounds__(256) void slice_mfma(
    unsigned short* __restrict__ xw, const unsigned short* __restrict__ wf,
    const float* __restrict__ bslice, const float* __restrict__ temp) {
  __shared__ unsigned short xs[4096];
  int t = threadIdx.x, w = t >> 6, l = t & 63;
  int blk = blockIdx.x;
  size_t base = (size_t)blk << 12;
  {
    int srow = t >> 2;
    const unsigned short* gp = xw + base + srow * 64 + ((t & 3) << 4);
    u16x8 a = *(const u16x8*)gp;
    u16x8 b = *(const u16x8*)(gp + 8);
    int sl0 = (t & 3) << 1, swz = srow & 7;
    *(u16x8*)&xs[srow * 64 + ((sl0 ^ swz) << 3)] = a;
    *(u16x8*)&xs[srow * 64 + (((sl0 + 1) ^ swz) << 3)] = b;
  }
  bf16x8 wsf[4][2];
#pragma unroll
  for (int gt = 0; gt < 4; gt++)
#pragma unroll
    for (int ks = 0; ks < 2; ks++)
      wsf[gt][ks] = *(const bf16x8*)(wf + (((gt << 1) + ks) * 64 + l) * 8);
  __syncthreads();

  int xr = (w << 4) + (l & 15);
  f32x4 acc[4];
#pragma unroll
  for (int gt = 0; gt < 4; gt++) acc[gt] = (f32x4){0.f, 0.f, 0.f, 0.f};
#pragma unroll
  for (int ks = 0; ks < 2; ks++) {
    int slot = (ks << 2) + (l >> 4);
    bf16x8 xf = *(const bf16x8*)&xs[xr * 64 + ((slot ^ (xr & 7)) << 3)];
#pragma unroll
    for (int gt = 0; gt < 4; gt++)
      acc[gt] = __builtin_amdgcn_mfma_f32_16x16x32_bf16(wsf[gt][ks], xf,
                                                        acc[gt], 0, 0, 0);
  }

  int gxr = (blk << 6) + xr;
  float invt = 1.0f / temp[gxr & 7];
  int qq = l >> 4;
  float lg[16];
  float mx = -1e30f;
#pragma unroll
  for (int gt = 0; gt < 4; gt++)
#pragma unroll
    for (int r = 0; r < 4; r++) {
      float v = (acc[gt][r] + bslice[(gt << 4) + (qq << 2) + r]) * invt;
      lg[(gt << 2) + r] = v;
      mx = fmaxf(mx, v);
    }
  mx = fmaxf(mx, __shfl_xor(mx, 16));
  mx = fmaxf(mx, __shfl_xor(mx, 32));
  float ssum = 0.f;
#pragma unroll
  for (int i = 0; i < 16; i++) {
    lg[i] = expf(lg[i] - mx);
    ssum += lg[i];
  }
  ssum += __shfl_xor(ssum, 16);
  ssum += __shfl_xor(ssum, 32);
  float inv = 1.0f / ssum;
  __syncthreads();
#pragma unroll
  for (int gt = 0; gt < 4; gt++) {
    int slot = (gt << 1) + (qq >> 1);
    int off = ((slot ^ (xr & 7)) << 3) + ((qq & 1) << 2);
    u16x4 pk;
    pk.x = f2b(lg[(gt << 2) + 0] * inv);
    pk.y = f2b(lg[(gt << 2) + 1] * inv);
    pk.z = f2b(lg[(gt << 2) + 2] * inv);
    pk.w = f2b(lg[(gt << 2) + 3] * inv);
    *(u16x4*)&xs[xr * 64 + off] = pk;
  }
  __syncthreads();
  {
    int rr = (w << 4) + (l >> 2);
    int sl = (l & 3) << 1, swz = rr & 7;
    u16x8 o0 = *(const u16x8*)&xs[rr * 64 + ((sl ^ swz) << 3)];
    u16x8 o1 = *(const u16x8*)&xs[rr * 64 + (((sl + 1) ^ swz) << 3)];
    unsigned short* op = xw + base + rr * 64 + ((l & 3) << 4);
    *(u16x8*)op = o0;
    *(u16x8*)(op + 8) = o1;
  }
}

// ---------------------------------------------------------------------------
// K6: pool via MFMA: tok_part[bid][g][d] = sum_{n in 512-chunk} w[n][g]*fx[n][d]
// Grid 512 = (bh:32) x (chunk:16). W-tile transposed into LDS with XOR-swizzled
// 16B slots (conflict-free writes + frag reads). fx from fxT (n-contiguous).
// norm_part[bid][g] = sum_n w[n][g] folded in (wave 0, from A-frags).
// ---------------------------------------------------------------------------
__global__ __launch_bounds__(256) void pool_mfma(
    const unsigned short* __restrict__ sw, const unsigned short* __restrict__ fxT,
    float* __restrict__ tok_part, float* __restrict__ norm_part) {
  __shared__ unsigned short wT[4096];  // [64 g][64 n], swizzled 16B slots
  int bid = blockIdx.x;
  int bh = bid >> 4, c = bid & 15;
  int b = bh >> 3, h = bh & 7;
  int t = threadIdx.x, w = t >> 6, l = t & 63;
  int n0 = c << 9;
  const int fr15 = l & 15, fs = l >> 4;
  f32x4 acc[4];
#pragma unroll
  for (int gt = 0; gt < 4; gt++) acc[gt] = (f32x4){0.f, 0.f, 0.f, 0.f};
  float nacc[4] = {0.f, 0.f, 0.f, 0.f};

  // this wave's d-stripe row in fxT: d = w*16 + fr15
  const unsigned short* fxrow =
      fxT + (size_t)(h * 64 + w * 16 + fr15) * 32768 + b * N_ + n0 + (fs << 3);

  for (int nn = 0; nn < 512; nn += 64) {
    // lane reads its own sw row (n = n0+nn+l), 16 cols at w*16
    size_t srow = ((size_t)(b * N_ + n0 + nn + l) * 8 + h) << 6;
    u16x8 a0 = *(const u16x8*)(sw + srow + w * 16);
    u16x8 a1 = *(const u16x8*)(sw + srow + w * 16 + 8);
    __syncthreads();  // prior frag reads done before overwrite
#pragma unroll
    for (int j = 0; j < 16; j++) {
      int g = (w << 4) + j;
      unsigned short v = (j < 8) ? (unsigned short)a0[j] : (unsigned short)a1[j - 8];
      wT[(g << 6) + (((l >> 3) ^ (g & 7)) << 3) + (l & 7)] = v;
    }
    __syncthreads();
#pragma unroll
    for (int kk = 0; kk < 2; kk++) {
      bf16x8 bfrag = *(const bf16x8*)(fxrow + nn + (kk << 5));
#pragma unroll
      for (int gt = 0; gt < 4; gt++) {
        int g = (gt << 4) + fr15;
        int slot = (kk << 2) + fs;
        bf16x8 af = *(const bf16x8*)&wT[(g << 6) + ((slot ^ (g & 7)) << 3)];
        acc[gt] = __builtin_amdgcn_mfma_f32_16x16x32_bf16(af, bfrag, acc[gt], 0, 0, 0);
        if (w == 0) {
#pragma unroll
          for (int j = 0; j < 8; j++) nacc[gt] += b2f((unsigned short)af[j]);
        }
      }
    }
  }
  float* op = tok_part + ((size_t)bid << 12);
#pragma unroll
  for (int gt = 0; gt < 4; gt++)
#pragma unroll
    for (int rr = 0; rr < 4; rr++)
      op[((gt << 4) + (fs << 2) + rr) * 64 + (w << 4) + fr15] = acc[gt][rr];
  if (w == 0) {
#pragma unroll
    for (int gt = 0; gt < 4; gt++) {
      float s = nacc[gt];
      s += __shfl_xor(s, 16);
      s += __shfl_xor(s, 32);
      if (l < 16) norm_part[(bid << 6) + (gt << 4) + l] = s;
    }
  }
}

// ---------------------------------------------------------------------------
// K6b: reduce tok_part chunks + norm_part -> normalized slice_tok fp32.
// ---------------------------------------------------------------------------
__global__ __launch_bounds__(256) void tok_reduce(
    const float* __restrict__ tok_part, const float* __restrict__ norm_part,
    float* __restrict__ stG) {
  int blk = blockIdx.x;
  int bh = blk >> 2, qq = blk & 3;
  int t = threadIdx.x;
  int e = (qq << 10) + (t << 2);
  int g = e >> 6;
  float s = 0.f;
  const float* np = norm_part + ((size_t)bh << 10);
#pragma unroll
  for (int c = 0; c < 16; c++) s += np[(c << 6) + g];
  float4 acc = make_float4(0.f, 0.f, 0.f, 0.f);
  const float* tp = tok_part + ((size_t)bh << 16) + e;
#pragma unroll
  for (int c = 0; c < 16; c++) {
    float4 v = *(const float4*)(tp + (c << 12));
    acc.x += v.x;
    acc.y += v.y;
    acc.z += v.z;
    acc.w += v.w;
  }
  float inv = 1.0f / (s + 1e-5f);
  acc.x *= inv;
  acc.y *= inv;
  acc.z *= inv;
  acc.w *= inv;
  *(float4*)(stG + ((size_t)bh << 12) + e) = acc;
}

// ---------------------------------------------------------------------------
// K7: token pipeline via MFMA (unchanged from round 3).
// ---------------------------------------------------------------------------
__device__ __forceinline__ float gelu_exact(float x) {
  return 0.5f * x * (1.0f + erff(x * 0.70710678118654752f));
}

__global__ __launch_bounds__(256) void token_mfma(
    const float* __restrict__ stG, const unsigned short* __restrict__ wfr,
    const float* __restrict__ tg, const float* __restrict__ tb,
    const float* __restrict__ bm1, const float* __restrict__ bm2,
    float* __restrict__ tokens) {
  __shared__ __align__(16) char smem[54272];
  unsigned short* stb = (unsigned short*)smem;
  float* st32 = (float*)(smem + 9216);
  unsigned short* hmld = (unsigned short*)(smem + 9216);
  unsigned short* qld = (unsigned short*)(smem + 26624);
  unsigned short* kld = (unsigned short*)(smem + 35840);
  unsigned short* vtl = (unsigned short*)(smem + 45056);

  int bh = blockIdx.x, t = threadIdx.x, w = t >> 6, l = t & 63;
  const int fr = l & 15, fq = l >> 4;

  {
    int r = t >> 2, c0 = (t & 3) << 4;
    const float* gp = stG + ((size_t)bh << 12) + r * 64 + c0;
    float4 a = *(const float4*)gp;
    float4 b = *(const float4*)(gp + 4);
    float4 c = *(const float4*)(gp + 8);
    float4 d = *(const float4*)(gp + 12);
    *(float4*)&st32[r * 68 + c0] = a;
    *(float4*)&st32[r * 68 + c0 + 4] = b;
    *(float4*)&st32[r * 68 + c0 + 8] = c;
    *(float4*)&st32[r * 68 + c0 + 12] = d;
    unsigned short tv[16];
    tv[0] = f2b(a.x); tv[1] = f2b(a.y); tv[2] = f2b(a.z); tv[3] = f2b(a.w);
    tv[4] = f2b(b.x); tv[5] = f2b(b.y); tv[6] = f2b(b.z); tv[7] = f2b(b.w);
    tv[8] = f2b(c.x); tv[9] = f2b(c.y); tv[10] = f2b(c.z); tv[11] = f2b(c.w);
    tv[12] = f2b(d.x); tv[13] = f2b(d.y); tv[14] = f2b(d.z); tv[15] = f2b(d.w);
    *(u16x8*)&stb[r * 72 + c0] = *(u16x8*)tv;
    *(u16x8*)&stb[r * 72 + c0 + 8] = *(u16x8*)(tv + 8);
  }
  __syncthreads();

  const int orow = (w << 4) + (fq << 2);

  {
    bf16x8 af[2];
#pragma unroll
    for (int ks = 0; ks < 2; ks++)
      af[ks] = *(const bf16x8*)&stb[((w << 4) + fr) * 72 + (ks << 5) + (fq << 3)];
    f32x4 aq[4], ak[4], av[4];
#pragma unroll
    for (int ct = 0; ct < 4; ct++) {
      aq[ct] = (f32x4){0.f, 0.f, 0.f, 0.f};
      ak[ct] = (f32x4){0.f, 0.f, 0.f, 0.f};
      av[ct] = (f32x4){0.f, 0.f, 0.f, 0.f};
    }
#pragma unroll
    for (int ct = 0; ct < 4; ct++)
#pragma unroll
      for (int ks = 0; ks < 2; ks++) {
        bf16x8 bq = *(const bf16x8*)&wfr[(((ct << 1) + ks) * 64 + l) * 8];
        aq[ct] = __builtin_amdgcn_mfma_f32_16x16x32_bf16(af[ks], bq, aq[ct], 0, 0, 0);
      }
#pragma unroll
    for (int ct = 0; ct < 4; ct++)
#pragma unroll
      for (int ks = 0; ks < 2; ks++) {
        bf16x8 bk = *(const bf16x8*)&wfr[((8 + (ct << 1) + ks) * 64 + l) * 8];
        ak[ct] = __builtin_amdgcn_mfma_f32_16x16x32_bf16(af[ks], bk, ak[ct], 0, 0, 0);
      }
#pragma unroll
    for (int ct = 0; ct < 4; ct++)
#pragma unroll
      for (int ks = 0; ks < 2; ks++) {
        bf16x8 bv = *(const bf16x8*)&wfr[((16 + (ct << 1) + ks) * 64 + l) * 8];
        av[ct] = __builtin_amdgcn_mfma_f32_16x16x32_bf16(af[ks], bv, av[ct], 0, 0, 0);
      }
#pragma unroll
    for (int ct = 0; ct < 4; ct++) {
#pragma unroll
      for (int rr = 0; rr < 4; rr++) {
        qld[(orow + rr) * 72 + (ct << 4) + fr] = f2b(aq[ct][rr]);
        kld[(orow + rr) * 72 + (ct << 4) + fr] = f2b(ak[ct][rr]);
      }
      u16x4 vp;
      vp.x = f2b(av[ct][0]);
      vp.y = f2b(av[ct][1]);
      vp.z = f2b(av[ct][2]);
      vp.w = f2b(av[ct][3]);
      *(u16x4*)&vtl[((ct << 4) + fr) * 72 + orow] = vp;
    }
  }
  __syncthreads();

  {
    bf16x8 aq[2];
#pragma unroll
    for (int ks = 0; ks < 2; ks++)
      aq[ks] = *(const bf16x8*)&qld[((w << 4) + fr) * 72 + (ks << 5) + (fq << 3)];
    f32x4 accs[4];
#pragma unroll
    for (int nt = 0; nt < 4; nt++) accs[nt] = (f32x4){0.f, 0.f, 0.f, 0.f};
#pragma unroll
    for (int nt = 0; nt < 4; nt++)
#pragma unroll
      for (int ks = 0; ks < 2; ks++) {
        bf16x8 bk = *(const bf16x8*)&kld[((nt << 4) + fr) * 72 + (ks << 5) + (fq << 3)];
        accs[nt] = __builtin_amdgcn_mfma_f32_16x16x32_bf16(aq[ks], bk, accs[nt], 0, 0, 0);
      }
#pragma unroll
    for (int rr = 0; rr < 4; rr++) {
      float v0 = accs[0][rr] * 0.125f, v1 = accs[1][rr] * 0.125f;
      float v2 = accs[2][rr] * 0.125f, v3 = accs[3][rr] * 0.125f;
      float mx = fmaxf(fmaxf(v0, v1), fmaxf(v2, v3));
      mx = fmaxf(mx, __shfl_xor(mx, 1));
      mx = fmaxf(mx, __shfl_xor(mx, 2));
      mx = fmaxf(mx, __shfl_xor(mx, 4));
      mx = fmaxf(mx, __shfl_xor(mx, 8));
      float e0 = expf(v0 - mx), e1 = expf(v1 - mx);
      float e2 = expf(v2 - mx), e3 = expf(v3 - mx);
      float ss = e0 + e1 + e2 + e3;
      ss += __shfl_xor(ss, 1);
      ss += __shfl_xor(ss, 2);
      ss += __shfl_xor(ss, 4);
      ss += __shfl_xor(ss, 8);
      float inv = 1.0f / ss;
      stb[(orow + rr) * 72 + 0 * 16 + fr] = f2b(e0 * inv);
      stb[(orow + rr) * 72 + 1 * 16 + fr] = f2b(e1 * inv);
      stb[(orow + rr) * 72 + 2 * 16 + fr] = f2b(e2 * inv);
      stb[(orow + rr) * 72 + 3 * 16 + fr] = f2b(e3 * inv);
    }
  }
  __syncthreads();

  float o16[4][4];
  {
    bf16x8 ap[2];
#pragma unroll
    for (int ks = 0; ks < 2; ks++)
      ap[ks] = *(const bf16x8*)&stb[((w << 4) + fr) * 72 + (ks << 5) + (fq << 3)];
    f32x4 acco[4];
#pragma unroll
    for (int ct = 0; ct < 4; ct++) acco[ct] = (f32x4){0.f, 0.f, 0.f, 0.f};
#pragma unroll
    for (int ct = 0; ct < 4; ct++)
#pragma unroll
      for (int ks = 0; ks < 2; ks++) {
        bf16x8 bv = *(const bf16x8*)&vtl[((ct << 4) + fr) * 72 + (ks << 5) + (fq << 3)];
        acco[ct] = __builtin_amdgcn_mfma_f32_16x16x32_bf16(ap[ks], bv, acco[ct], 0, 0, 0);
      }
    float tgv[4], tbv[4];
#pragma unroll
    for (int ct = 0; ct < 4; ct++) {
      tgv[ct] = tg[(ct << 4) + fr];
      tbv[ct] = tb[(ct << 4) + fr];
    }
#pragma unroll
    for (int ct = 0; ct < 4; ct++)
#pragma unroll
      for (int rr = 0; rr < 4; rr++)
        o16[ct][rr] = acco[ct][rr] + st32[(orow + rr) * 68 + (ct << 4) + fr];
#pragma unroll
    for (int rr = 0; rr < 4; rr++) {
      float sm = o16[0][rr] + o16[1][rr] + o16[2][rr] + o16[3][rr];
      float sq = o16[0][rr] * o16[0][rr] + o16[1][rr] * o16[1][rr] +
                 o16[2][rr] * o16[2][rr] + o16[3][rr] * o16[3][rr];
      sm += __shfl_xor(sm, 1);
      sm += __shfl_xor(sm, 2);
      sm += __shfl_xor(sm, 4);
      sm += __shfl_xor(sm, 8);
      sq += __shfl_xor(sq, 1);
      sq += __shfl_xor(sq, 2);
      sq += __shfl_xor(sq, 4);
      sq += __shfl_xor(sq, 8);
      float mean = sm * (1.0f / 64.0f);
      float var = sq * (1.0f / 64.0f) - mean * mean;
      float rstd = rsqrtf(var + 1e-5f);
#pragma unroll
      for (int ct = 0; ct < 4; ct++) {
        float hv = (o16[ct][rr] - mean) * rstd * tgv[ct] + tbv[ct];
        qld[(orow + rr) * 72 + (ct << 4) + fr] = f2b(hv);
      }
    }
  }
  __syncthreads();

  {
    bf16x8 ah[2];
#pragma unroll
    for (int ks = 0; ks < 2; ks++)
      ah[ks] = *(const bf16x8*)&qld[((w << 4) + fr) * 72 + (ks << 5) + (fq << 3)];
    f32x4 accm[8];
#pragma unroll
    for (int et = 0; et < 8; et++) accm[et] = (f32x4){0.f, 0.f, 0.f, 0.f};
#pragma unroll
    for (int et = 0; et < 8; et++)
#pragma unroll
      for (int ks = 0; ks < 2; ks++) {
        bf16x8 bm = *(const bf16x8*)&wfr[((24 + (et << 1) + ks) * 64 + l) * 8];
        accm[et] = __builtin_amdgcn_mfma_f32_16x16x32_bf16(ah[ks], bm, accm[et], 0, 0, 0);
      }
#pragma unroll
    for (int et = 0; et < 8; et++) {
      float bv = bm1[(et << 4) + fr];
#pragma unroll
      for (int rr = 0; rr < 4; rr++) {
        float x = accm[et][rr] + bv;
        hmld[(orow + rr) * 136 + (et << 4) + fr] = f2b(gelu_exact(x));
      }
    }
  }
  __syncthreads();

  {
    bf16x8 ahm[4];
#pragma unroll
    for (int ks = 0; ks < 4; ks++)
      ahm[ks] = *(const bf16x8*)&hmld[((w << 4) + fr) * 136 + (ks << 5) + (fq << 3)];
    f32x4 acc2[4];
#pragma unroll
    for (int ct = 0; ct < 4; ct++) acc2[ct] = (f32x4){0.f, 0.f, 0.f, 0.f};
#pragma unroll
    for (int ct = 0; ct < 4; ct++)
#pragma unroll
      for (int ks = 0; ks < 4; ks++) {
        bf16x8 bw = *(const bf16x8*)&wfr[((40 + (ct << 2) + ks) * 64 + l) * 8];
        acc2[ct] = __builtin_amdgcn_mfma_f32_16x16x32_bf16(ahm[ks], bw, acc2[ct], 0, 0, 0);
      }
    float* tout = tokens + ((size_t)bh << 12);
#pragma unroll
    for (int ct = 0; ct < 4; ct++) {
      float bv = bm2[(ct << 4) + fr];
#pragma unroll
      for (int rr = 0; rr < 4; rr++)
        tout[(orow + rr) * 64 + (ct << 4) + fr] = acc2[ct][rr] + bv + o16[ct][rr];
    }
  }
}

// ---------------------------------------------------------------------------
// K8: deslice (unchanged).
// ---------------------------------------------------------------------------
__global__ __launch_bounds__(256) void deslice_bf16(
    const float* __restrict__ tokens, const unsigned short* __restrict__ sw,
    unsigned short* __restrict__ outx) {
  __shared__ float tok[4096];
  __shared__ float wl[64][65];
  int t = threadIdx.x;
  int blk = blockIdx.x;
  int nc = blk & 127, h = (blk >> 7) & 7, b = blk >> 10;
  const float* tp = tokens + ((size_t)(b * 8 + h) << 12);
#pragma unroll
  for (int i = 0; i < 16; i++) tok[t + i * 256] = tp[t + i * 256];
  int n0 = nc << 6;
  {
    int r = t >> 2, cs = (t & 3) << 4;
    size_t rb = ((size_t)(b * N_ + n0 + r) * 8 + h) << 6;
    u16x8 a = *(const u16x8*)(sw + rb + cs);
    u16x8 bq = *(const u16x8*)(sw + rb + cs + 8);
#pragma unroll
    for (int i = 0; i < 8; i++) {
      wl[r][cs + i] = b2f(a[i]);
      wl[r][cs + 8 + i] = b2f(bq[i]);
    }
  }
  __syncthreads();
  int nl = t >> 2, d0 = (t & 3) << 4;
  float acc[16];
#pragma unroll
  for (int j = 0; j < 16; j++) acc[j] = 0.f;
  for (int gi = 0; gi < 64; gi++) {
    float wv = wl[nl][gi];
    const float* tr = &tok[(gi << 6) + d0];
#pragma unroll
    for (int j = 0; j < 16; j++) acc[j] += wv * tr[j];
  }
  unsigned short ov[16];
#pragma unroll
  for (int j = 0; j < 16; j++) ov[j] = f2b(acc[j]);
  unsigned short* op = outx + (((size_t)(b * N_ + n0 + nl) * 8 + h) << 6) + d0;
  *(u16x8*)op = *(u16x8*)ov;
  *(u16x8*)(op + 8) = *(u16x8*)(ov + 8);
}

// ---------------------------------------------------------------------------
extern "C" void kernel_launch(void* const* d_in, const int* in_sizes, int n_in,
                              void* d_out, int out_size, void* d_ws,
                              size_t ws_size, hipStream_t stream) {
  const float* fx = (const float*)d_in[0];
  const float* ln1g = (const float*)d_in[1];
  const float* ln1b = (const float*)d_in[2];
  const float* Wx = (const float*)d_in[3];
  const float* bx = (const float*)d_in[4];
  const float* Wfx = (const float*)d_in[5];
  const float* bfx = (const float*)d_in[6];
  const float* Wsl = (const float*)d_in[7];
  const float* bsl = (const float*)d_in[8];
  const float* temp = (const float*)d_in[9];
  const float* Wq = (const float*)d_in[10];
  const float* Wk = (const float*)d_in[11];
  const float* Wv = (const float*)d_in[12];
  const float* Wout = (const float*)d_in[13];
  const float* bout = (const float*)d_in[14];
  const float* tlng = (const float*)d_in[15];
  const float* tlnb = (const float*)d_in[16];
  const float* Wm1 = (const float*)d_in[17];
  const float* bm1 = (const float*)d_in[18];
  const float* Wm2 = (const float*)d_in[19];
  const float* bm2 = (const float*)d_in[20];
  float* out = (float*)d_out;

  char* p = (char*)d_ws;
  const size_t MC2 = (size_t)M_ * 512 * 2;
  unsigned short* fxn = (unsigned short*)p;  p += MC2;
  unsigned short* buf1 = (unsigned short*)p; p += MC2;  // x_mid -> slice_w
  unsigned short* bufT = (unsigned short*)p; p += MC2;  // fxT [512][32768] -> out_x [M][512]
  unsigned short* WtX = (unsigned short*)p;  p += 512 * 512 * 2;
  unsigned short* WtF = (unsigned short*)p;  p += 512 * 512 * 2;
  unsigned short* WtO = (unsigned short*)p;  p += 512 * 512 * 2;
  unsigned short* wsf = (unsigned short*)p;  p += 8192;
  unsigned short* wfr = (unsigned short*)p;  p += 56 * 512 * 2;
  float* tok_part = (float*)p;  p += (size_t)512 * 4096 * 4;
  float* norm_part = (float*)p; p += (size_t)512 * 64 * 4;
  float* tokens = (float*)p;    p += (size_t)32 * 4096 * 4;
  float* stG = (float*)p;       p += (size_t)32 * 4096 * 4;

  ln_bf16<<<M_ / 4, 256, 0, stream>>>(fx, ln1g, ln1b, fxn);
  dim3 wg(8, 8);
  wconv_t<<<wg, 256, 0, stream>>>(Wx, WtX);
  wconv_t<<<wg, 256, 0, stream>>>(Wfx, WtF);
  wconv_t<<<wg, 256, 0, stream>>>(Wout, WtO);
  wslice_prep<<<1, 256, 0, stream>>>(Wsl, wsf);
  wfrag_prep<<<1, 256, 0, stream>>>(Wq, Wk, Wv, Wm1, Wm2, wfr);
  // x_mid: [M,512]
  gemm_bf16<0, false, true, false><<<1024, 256, 0, stream>>>(fxn, WtX, bx, nullptr, buf1, 512);
  // fx_mid TRANSPOSED: fxT[(h*64+d)][b*8192+n] = (Wfx^T . fx_norm^T)
  gemm_bf16<1, true, true, false><<<1024, 256, 0, stream>>>(WtF, fxn, bfx, nullptr, bufT, 32768);
  slice_mfma<<<4096, 256, 0, stream>>>(buf1, wsf, bsl, temp);
  pool_mfma<<<512, 256, 0, stream>>>(buf1, bufT, tok_part, norm_part);
  tok_reduce<<<128, 256, 0, stream>>>(tok_part, norm_part, stG);
  token_mfma<<<32, 256, 0, stream>>>(stG, wfr, tlng, tlnb, bm1, bm2, tokens);
  deslice_bf16<<<4096, 256, 0, stream>>>(tokens, buf1, bufT);
  gemm_bf16<0, false, false, true><<<1024, 256, 0, stream>>>(bufT, WtO, bout, fxn, out, 512);
}

// Round 5
// 192.930 us; speedup vs baseline: 6.1222x; 1.1028x over previous
//
#include <hip/hip_runtime.h>
#include <math.h>

#define B_ 4
#define N_ 8192
#define C_ 512
#define H_ 8
#define M_ (B_ * N_) /* 32768 */

typedef __attribute__((ext_vector_type(8))) short bf16x8;
typedef __attribute__((ext_vector_type(4))) float f32x4;
typedef __attribute__((ext_vector_type(8))) unsigned short u16x8;
typedef __attribute__((ext_vector_type(4))) unsigned short u16x4;

__device__ __forceinline__ float b2f(unsigned short u) {
  union { unsigned int i; float f; } v;
  v.i = ((unsigned int)u) << 16;
  return v.f;
}
__device__ __forceinline__ unsigned short f2b(float f) {
  union { float f; unsigned int i; } v;
  v.f = f;
  unsigned int r = v.i + 0x7fff + ((v.i >> 16) & 1);
  return (unsigned short)(r >> 16);
}
__device__ __forceinline__ void gl_lds16(const void* g, void* l) {
  __builtin_amdgcn_global_load_lds(
      (const __attribute__((address_space(1))) unsigned int*)g,
      (__attribute__((address_space(3))) unsigned int*)l, 16, 0, 0);
}

// ---------------------------------------------------------------------------
// K1: LayerNorm over C=512 -> bf16. One wave per row.
// ---------------------------------------------------------------------------
__global__ __launch_bounds__(256) void ln_bf16(
    const float* __restrict__ x, const float* __restrict__ gam,
    const float* __restrict__ bet, unsigned short* __restrict__ y) {
  int wave = threadIdx.x >> 6, lane = threadIdx.x & 63;
  int row = (blockIdx.x << 2) + wave;
  const float4* xr = (const float4*)(x + (size_t)row * C_);
  float4 v0 = xr[lane], v1 = xr[lane + 64];
  float s = v0.x + v0.y + v0.z + v0.w + v1.x + v1.y + v1.z + v1.w;
  float q = v0.x * v0.x + v0.y * v0.y + v0.z * v0.z + v0.w * v0.w +
            v1.x * v1.x + v1.y * v1.y + v1.z * v1.z + v1.w * v1.w;
#pragma unroll
  for (int off = 32; off; off >>= 1) {
    s += __shfl_xor(s, off);
    q += __shfl_xor(q, off);
  }
  float mean = s * (1.0f / C_);
  float var = q * (1.0f / C_) - mean * mean;
  float rstd = rsqrtf(var + 1e-5f);
  const float4* gr = (const float4*)gam;
  const float4* br = (const float4*)bet;
  float4 g0 = gr[lane], g1 = gr[lane + 64];
  float4 b0 = br[lane], b1 = br[lane + 64];
  u16x4 oa, ob;
  oa.x = f2b((v0.x - mean) * rstd * g0.x + b0.x);
  oa.y = f2b((v0.y - mean) * rstd * g0.y + b0.y);
  oa.z = f2b((v0.z - mean) * rstd * g0.z + b0.z);
  oa.w = f2b((v0.w - mean) * rstd * g0.w + b0.w);
  ob.x = f2b((v1.x - mean) * rstd * g1.x + b1.x);
  ob.y = f2b((v1.y - mean) * rstd * g1.y + b1.y);
  ob.z = f2b((v1.z - mean) * rstd * g1.z + b1.z);
  ob.w = f2b((v1.w - mean) * rstd * g1.w + b1.w);
  unsigned short* yr = y + (size_t)row * C_;
  *(u16x4*)(yr + (lane << 2)) = oa;
  *(u16x4*)(yr + 256 + (lane << 2)) = ob;
}

// ---------------------------------------------------------------------------
// K2: weight fp32 [512,512] (k-major) -> bf16 transposed Wt[n][k]
// ---------------------------------------------------------------------------
__global__ __launch_bounds__(256) void wconv_t(const float* __restrict__ W,
                                               unsigned short* __restrict__ Wt) {
  __shared__ float tile[64][65];
  int t = threadIdx.x;
  int r0 = (int)blockIdx.y << 6, c0 = (int)blockIdx.x << 6;
  int lr = t >> 4, lc = (t & 15) << 2;
#pragma unroll
  for (int p = 0; p < 4; p++) {
    float4 v = *(const float4*)(W + (size_t)(r0 + lr + p * 16) * 512 + c0 + lc);
    tile[lr + p * 16][lc + 0] = v.x;
    tile[lr + p * 16][lc + 1] = v.y;
    tile[lr + p * 16][lc + 2] = v.z;
    tile[lr + p * 16][lc + 3] = v.w;
  }
  __syncthreads();
  int on = t >> 2, ok = (t & 3) << 4;
  unsigned short tmp[16];
#pragma unroll
  for (int j = 0; j < 16; j++) tmp[j] = f2b(tile[ok + j][on]);
  unsigned short* op = Wt + (size_t)(c0 + on) * 512 + r0 + ok;
#pragma unroll
  for (int j4 = 0; j4 < 4; j4++) *(u16x4*)(op + (j4 << 2)) = *(u16x4*)(tmp + (j4 << 2));
}

// ---------------------------------------------------------------------------
// K3: precompute Wslice^T bf16 fragments
// ---------------------------------------------------------------------------
__global__ __launch_bounds__(256) void wslice_prep(const float* __restrict__ Ws,
                                                   unsigned short* __restrict__ wf) {
  int t = threadIdx.x;
#pragma unroll
  for (int i = 0; i < 2; i++) {
    int idx = t + i * 256;
    int f = idx >> 6, l = idx & 63;
    int gt = f >> 1, ks = f & 1;
    int g = (gt << 4) + (l & 15);
    int d0 = (ks << 5) + ((l >> 4) << 3);
    unsigned short v[8];
#pragma unroll
    for (int jj = 0; jj < 8; jj++) v[jj] = f2b(Ws[(size_t)(d0 + jj) * 64 + g]);
    *(u16x4*)(wf + idx * 8) = *(u16x4*)v;
    *(u16x4*)(wf + idx * 8 + 4) = *(u16x4*)(v + 4);
  }
}

// ---------------------------------------------------------------------------
// K3b: precompute B-operand fragments for token pipeline weights.
// ---------------------------------------------------------------------------
__global__ __launch_bounds__(256) void wfrag_prep(
    const float* __restrict__ Wq, const float* __restrict__ Wk,
    const float* __restrict__ Wv, const float* __restrict__ Wm1,
    const float* __restrict__ Wm2, unsigned short* __restrict__ wfr) {
  int t = threadIdx.x;
  for (int task = t; task < 56 * 64; task += 256) {
    int fid = task >> 6, l = task & 63;
    const float* W;
    int stride, ct, ks;
    if (fid < 24) {
      W = (fid < 8) ? Wq : (fid < 16) ? Wk : Wv;
      int e = fid & 7;
      ct = e >> 1;
      ks = e & 1;
      stride = 64;
    } else if (fid < 40) {
      W = Wm1;
      int e = fid - 24;
      ct = e >> 1;
      ks = e & 1;
      stride = 128;
    } else {
      W = Wm2;
      int e = fid - 40;
      ct = e >> 2;
      ks = e & 3;
      stride = 64;
    }
    int d0 = (ks << 5) + ((l >> 4) << 3);
    int c = (ct << 4) + (l & 15);
    unsigned short v[8];
#pragma unroll
    for (int j = 0; j < 8; j++) v[j] = f2b(W[(size_t)(d0 + j) * stride + c]);
    *(u16x4*)(wfr + task * 8) = *(u16x4*)v;
    *(u16x4*)(wfr + task * 8 + 4) = *(u16x4*)(v + 4);
  }
}

// ---------------------------------------------------------------------------
// K3c: precompute tokens^T A-operand fragments for deslice.
// frag(bh, mt, ks): lane l elem j = tokens[bh][g=ks*32+(l>>4)*8+j][d=mt*16+(l&15)]
// ---------------------------------------------------------------------------
__global__ __launch_bounds__(256) void tokfrag_prep(
    const float* __restrict__ tokens, unsigned short* __restrict__ wtokf) {
  int bh = blockIdx.x, t = threadIdx.x, w = t >> 6, l = t & 63;
  const float* tp = tokens + ((size_t)bh << 12);
#pragma unroll
  for (int fid = w; fid < 8; fid += 4) {
    int mt = fid >> 1, ks = fid & 1;
    int d = (mt << 4) + (l & 15);
    int g0 = (ks << 5) + ((l >> 4) << 3);
    unsigned short v[8];
#pragma unroll
    for (int j = 0; j < 8; j++) v[j] = f2b(tp[(g0 + j) * 64 + d]);
    unsigned short* op = wtokf + (((size_t)bh << 3) + fid) * 512 + (l << 3);
    *(u16x4*)op = *(u16x4*)v;
    *(u16x4*)(op + 4) = *(u16x4*)(v + 4);
  }
}

// ---------------------------------------------------------------------------
// K4: bf16 MFMA GEMM  D[m,col] = A[m,:] . Bt[col,:] + bias (+resid)
// ---------------------------------------------------------------------------
template <int DEC, bool BIASROW, bool OUTBF, bool RES>
__global__ __launch_bounds__(256) void gemm_bf16(
    const unsigned short* __restrict__ A, const unsigned short* __restrict__ Bt,
    const float* __restrict__ bias, const unsigned short* __restrict__ resid,
    void* __restrict__ Cout, size_t ldC) {
  __shared__ unsigned short lds[8192];
  const int t = threadIdx.x;
  const int w = t >> 6, l = t & 63;
  int bid = blockIdx.x;
  int xcd = bid & 7, q = bid >> 3;
  int bm, bn;
  if (DEC == 0) {
    bm = ((xcd << 5) + (q >> 2)) << 7;
    bn = (q & 3) << 7;
  } else {
    bn = ((xcd << 5) + (q >> 2)) << 7;
    bm = (q & 3) << 7;
  }
  const int wm = (w >> 1) << 6, wn = (w & 1) << 6;
  f32x4 acc[4][4];
#pragma unroll
  for (int mt = 0; mt < 4; mt++)
#pragma unroll
    for (int nt = 0; nt < 4; nt++) acc[mt][nt] = (f32x4){0.f, 0.f, 0.f, 0.f};

  const int srow = t >> 2;
  const int scol = (t & 3) << 3;
  const unsigned short* gA0 = A + (size_t)(bm + srow) * 512 + scol;
  const unsigned short* gA1 = A + (size_t)(bm + 64 + srow) * 512 + scol;
  const unsigned short* gB0 = Bt + (size_t)(bn + srow) * 512 + scol;
  const unsigned short* gB1 = Bt + (size_t)(bn + 64 + srow) * 512 + scol;
  const int fr = l & 15, fq = (l >> 4) << 3;

  for (int k0 = 0; k0 < 512; k0 += 32) {
    gl_lds16(gA0 + k0, lds + (w << 9));
    gl_lds16(gA1 + k0, lds + 2048 + (w << 9));
    gl_lds16(gB0 + k0, lds + 4096 + (w << 9));
    gl_lds16(gB1 + k0, lds + 6144 + (w << 9));
    __syncthreads();
    bf16x8 af[4], bfr[4];
#pragma unroll
    for (int mt = 0; mt < 4; mt++)
      af[mt] = *(const bf16x8*)&lds[(wm + mt * 16 + fr) * 32 + fq];
#pragma unroll
    for (int nt = 0; nt < 4; nt++)
      bfr[nt] = *(const bf16x8*)&lds[4096 + (wn + nt * 16 + fr) * 32 + fq];
#pragma unroll
    for (int mt = 0; mt < 4; mt++)
#pragma unroll
      for (int nt = 0; nt < 4; nt++)
        acc[mt][nt] = __builtin_amdgcn_mfma_f32_16x16x32_bf16(
            af[mt], bfr[nt], acc[mt][nt], 0, 0, 0);
    __syncthreads();
  }

  const int col0 = bn + wn + (l & 15);
  const int row0 = bm + wm + ((l >> 4) << 2);
#pragma unroll
  for (int mt = 0; mt < 4; mt++) {
#pragma unroll
    for (int j = 0; j < 4; j++) {
      int row = row0 + mt * 16 + j;
#pragma unroll
      for (int nt = 0; nt < 4; nt++) {
        int col = col0 + nt * 16;
        float v = acc[mt][nt][j] + (BIASROW ? bias[row] : bias[col]);
        if (RES) v += b2f(resid[(size_t)row * ldC + col]);
        if (OUTBF)
          ((unsigned short*)Cout)[(size_t)row * ldC + col] = f2b(v);
        else
          ((float*)Cout)[(size_t)row * ldC + col] = v;
      }
    }
  }
}

// ---------------------------------------------------------------------------
// K5: slice softmax via MFMA (unchanged).
// ---------------------------------------------------------------------------
__global__ __launch_bounds__(256) void slice_mfma(
    unsigned short* __restrict__ xw, const unsigned short* __restrict__ wf,
    const float* __restrict__ bslice, const float* __restrict__ temp) {
  __shared__ unsigned short xs[4096];
  int t = threadIdx.x, w = t >> 6, l = t & 63;
  int blk = blockIdx.x;
  size_t base = (size_t)blk << 12;
  {
    int srow = t >> 2;
    const unsigned short* gp = xw + base + srow * 64 + ((t & 3) << 4);
    u16x8 a = *(const u16x8*)gp;
    u16x8 b = *(const u16x8*)(gp + 8);
    int sl0 = (t & 3) << 1, swz = srow & 7;
    *(u16x8*)&xs[srow * 64 + ((sl0 ^ swz) << 3)] = a;
    *(u16x8*)&xs[srow * 64 + (((sl0 + 1) ^ swz) << 3)] = b;
  }
  bf16x8 wsf[4][2];
#pragma unroll
  for (int gt = 0; gt < 4; gt++)
#pragma unroll
    for (int ks = 0; ks < 2; ks++)
      wsf[gt][ks] = *(const bf16x8*)(wf + (((gt << 1) + ks) * 64 + l) * 8);
  __syncthreads();

  int xr = (w << 4) + (l & 15);
  f32x4 acc[4];
#pragma unroll
  for (int gt = 0; gt < 4; gt++) acc[gt] = (f32x4){0.f, 0.f, 0.f, 0.f};
#pragma unroll
  for (int ks = 0; ks < 2; ks++) {
    int slot = (ks << 2) + (l >> 4);
    bf16x8 xf = *(const bf16x8*)&xs[xr * 64 + ((slot ^ (xr & 7)) << 3)];
#pragma unroll
    for (int gt = 0; gt < 4; gt++)
      acc[gt] = __builtin_amdgcn_mfma_f32_16x16x32_bf16(wsf[gt][ks], xf,
                                                        acc[gt], 0, 0, 0);
  }

  int gxr = (blk << 6) + xr;
  float invt = 1.0f / temp[gxr & 7];
  int qq = l >> 4;
  float lg[16];
  float mx = -1e30f;
#pragma unroll
  for (int gt = 0; gt < 4; gt++)
#pragma unroll
    for (int r = 0; r < 4; r++) {
      float v = (acc[gt][r] + bslice[(gt << 4) + (qq << 2) + r]) * invt;
      lg[(gt << 2) + r] = v;
      mx = fmaxf(mx, v);
    }
  mx = fmaxf(mx, __shfl_xor(mx, 16));
  mx = fmaxf(mx, __shfl_xor(mx, 32));
  float ssum = 0.f;
#pragma unroll
  for (int i = 0; i < 16; i++) {
    lg[i] = expf(lg[i] - mx);
    ssum += lg[i];
  }
  ssum += __shfl_xor(ssum, 16);
  ssum += __shfl_xor(ssum, 32);
  float inv = 1.0f / ssum;
  __syncthreads();
#pragma unroll
  for (int gt = 0; gt < 4; gt++) {
    int slot = (gt << 1) + (qq >> 1);
    int off = ((slot ^ (xr & 7)) << 3) + ((qq & 1) << 2);
    u16x4 pk;
    pk.x = f2b(lg[(gt << 2) + 0] * inv);
    pk.y = f2b(lg[(gt << 2) + 1] * inv);
    pk.z = f2b(lg[(gt << 2) + 2] * inv);
    pk.w = f2b(lg[(gt << 2) + 3] * inv);
    *(u16x4*)&xs[xr * 64 + off] = pk;
  }
  __syncthreads();
  {
    int rr = (w << 4) + (l >> 2);
    int sl = (l & 3) << 1, swz = rr & 7;
    u16x8 o0 = *(const u16x8*)&xs[rr * 64 + ((sl ^ swz) << 3)];
    u16x8 o1 = *(const u16x8*)&xs[rr * 64 + (((sl + 1) ^ swz) << 3)];
    unsigned short* op = xw + base + rr * 64 + ((l & 3) << 4);
    *(u16x8*)op = o0;
    *(u16x8*)(op + 8) = o1;
  }
}

// ---------------------------------------------------------------------------
// K6: pool via MFMA (unchanged from round 4).
// ---------------------------------------------------------------------------
__global__ __launch_bounds__(256) void pool_mfma(
    const unsigned short* __restrict__ sw, const unsigned short* __restrict__ fxT,
    float* __restrict__ tok_part, float* __restrict__ norm_part) {
  __shared__ unsigned short wT[4096];
  int bid = blockIdx.x;
  int bh = bid >> 4, c = bid & 15;
  int b = bh >> 3, h = bh & 7;
  int t = threadIdx.x, w = t >> 6, l = t & 63;
  int n0 = c << 9;
  const int fr15 = l & 15, fs = l >> 4;
  f32x4 acc[4];
#pragma unroll
  for (int gt = 0; gt < 4; gt++) acc[gt] = (f32x4){0.f, 0.f, 0.f, 0.f};
  float nacc[4] = {0.f, 0.f, 0.f, 0.f};

  const unsigned short* fxrow =
      fxT + (size_t)(h * 64 + w * 16 + fr15) * 32768 + b * N_ + n0 + (fs << 3);

  for (int nn = 0; nn < 512; nn += 64) {
    size_t srow = ((size_t)(b * N_ + n0 + nn + l) * 8 + h) << 6;
    u16x8 a0 = *(const u16x8*)(sw + srow + w * 16);
    u16x8 a1 = *(const u16x8*)(sw + srow + w * 16 + 8);
    __syncthreads();
#pragma unroll
    for (int j = 0; j < 16; j++) {
      int g = (w << 4) + j;
      unsigned short v = (j < 8) ? (unsigned short)a0[j] : (unsigned short)a1[j - 8];
      wT[(g << 6) + (((l >> 3) ^ (g & 7)) << 3) + (l & 7)] = v;
    }
    __syncthreads();
#pragma unroll
    for (int kk = 0; kk < 2; kk++) {
      bf16x8 bfrag = *(const bf16x8*)(fxrow + nn + (kk << 5));
#pragma unroll
      for (int gt = 0; gt < 4; gt++) {
        int g = (gt << 4) + fr15;
        int slot = (kk << 2) + fs;
        bf16x8 af = *(const bf16x8*)&wT[(g << 6) + ((slot ^ (g & 7)) << 3)];
        acc[gt] = __builtin_amdgcn_mfma_f32_16x16x32_bf16(af, bfrag, acc[gt], 0, 0, 0);
        if (w == 0) {
#pragma unroll
          for (int j = 0; j < 8; j++) nacc[gt] += b2f((unsigned short)af[j]);
        }
      }
    }
  }
  float* op = tok_part + ((size_t)bid << 12);
#pragma unroll
  for (int gt = 0; gt < 4; gt++)
#pragma unroll
    for (int rr = 0; rr < 4; rr++)
      op[((gt << 4) + (fs << 2) + rr) * 64 + (w << 4) + fr15] = acc[gt][rr];
  if (w == 0) {
#pragma unroll
    for (int gt = 0; gt < 4; gt++) {
      float s = nacc[gt];
      s += __shfl_xor(s, 16);
      s += __shfl_xor(s, 32);
      if (l < 16) norm_part[(bid << 6) + (gt << 4) + l] = s;
    }
  }
}

// ---------------------------------------------------------------------------
// K6b: reduce tok_part chunks + norm_part -> normalized slice_tok fp32.
// ---------------------------------------------------------------------------
__global__ __launch_bounds__(256) void tok_reduce(
    const float* __restrict__ tok_part, const float* __restrict__ norm_part,
    float* __restrict__ stG) {
  int blk = blockIdx.x;
  int bh = blk >> 2, qq = blk & 3;
  int t = threadIdx.x;
  int e = (qq << 10) + (t << 2);
  int g = e >> 6;
  float s = 0.f;
  const float* np = norm_part + ((size_t)bh << 10);
#pragma unroll
  for (int c = 0; c < 16; c++) s += np[(c << 6) + g];
  float4 acc = make_float4(0.f, 0.f, 0.f, 0.f);
  const float* tp = tok_part + ((size_t)bh << 16) + e;
#pragma unroll
  for (int c = 0; c < 16; c++) {
    float4 v = *(const float4*)(tp + (c << 12));
    acc.x += v.x;
    acc.y += v.y;
    acc.z += v.z;
    acc.w += v.w;
  }
  float inv = 1.0f / (s + 1e-5f);
  acc.x *= inv;
  acc.y *= inv;
  acc.z *= inv;
  acc.w *= inv;
  *(float4*)(stG + ((size_t)bh << 12) + e) = acc;
}

// ---------------------------------------------------------------------------
// K7: token pipeline via MFMA (unchanged from round 3).
// ---------------------------------------------------------------------------
__device__ __forceinline__ float gelu_exact(float x) {
  return 0.5f * x * (1.0f + erff(x * 0.70710678118654752f));
}

__global__ __launch_bounds__(256) void token_mfma(
    const float* __restrict__ stG, const unsigned short* __restrict__ wfr,
    const float* __restrict__ tg, const float* __restrict__ tb,
    const float* __restrict__ bm1, const float* __restrict__ bm2,
    float* __restrict__ tokens) {
  __shared__ __align__(16) char smem[54272];
  unsigned short* stb = (unsigned short*)smem;
  float* st32 = (float*)(smem + 9216);
  unsigned short* hmld = (unsigned short*)(smem + 9216);
  unsigned short* qld = (unsigned short*)(smem + 26624);
  unsigned short* kld = (unsigned short*)(smem + 35840);
  unsigned short* vtl = (unsigned short*)(smem + 45056);

  int bh = blockIdx.x, t = threadIdx.x, w = t >> 6, l = t & 63;
  const int fr = l & 15, fq = l >> 4;

  {
    int r = t >> 2, c0 = (t & 3) << 4;
    const float* gp = stG + ((size_t)bh << 12) + r * 64 + c0;
    float4 a = *(const float4*)gp;
    float4 b = *(const float4*)(gp + 4);
    float4 c = *(const float4*)(gp + 8);
    float4 d = *(const float4*)(gp + 12);
    *(float4*)&st32[r * 68 + c0] = a;
    *(float4*)&st32[r * 68 + c0 + 4] = b;
    *(float4*)&st32[r * 68 + c0 + 8] = c;
    *(float4*)&st32[r * 68 + c0 + 12] = d;
    unsigned short tv[16];
    tv[0] = f2b(a.x); tv[1] = f2b(a.y); tv[2] = f2b(a.z); tv[3] = f2b(a.w);
    tv[4] = f2b(b.x); tv[5] = f2b(b.y); tv[6] = f2b(b.z); tv[7] = f2b(b.w);
    tv[8] = f2b(c.x); tv[9] = f2b(c.y); tv[10] = f2b(c.z); tv[11] = f2b(c.w);
    tv[12] = f2b(d.x); tv[13] = f2b(d.y); tv[14] = f2b(d.z); tv[15] = f2b(d.w);
    *(u16x8*)&stb[r * 72 + c0] = *(u16x8*)tv;
    *(u16x8*)&stb[r * 72 + c0 + 8] = *(u16x8*)(tv + 8);
  }
  __syncthreads();

  const int orow = (w << 4) + (fq << 2);

  {
    bf16x8 af[2];
#pragma unroll
    for (int ks = 0; ks < 2; ks++)
      af[ks] = *(const bf16x8*)&stb[((w << 4) + fr) * 72 + (ks << 5) + (fq << 3)];
    f32x4 aq[4], ak[4], av[4];
#pragma unroll
    for (int ct = 0; ct < 4; ct++) {
      aq[ct] = (f32x4){0.f, 0.f, 0.f, 0.f};
      ak[ct] = (f32x4){0.f, 0.f, 0.f, 0.f};
      av[ct] = (f32x4){0.f, 0.f, 0.f, 0.f};
    }
#pragma unroll
    for (int ct = 0; ct < 4; ct++)
#pragma unroll
      for (int ks = 0; ks < 2; ks++) {
        bf16x8 bq = *(const bf16x8*)&wfr[(((ct << 1) + ks) * 64 + l) * 8];
        aq[ct] = __builtin_amdgcn_mfma_f32_16x16x32_bf16(af[ks], bq, aq[ct], 0, 0, 0);
      }
#pragma unroll
    for (int ct = 0; ct < 4; ct++)
#pragma unroll
      for (int ks = 0; ks < 2; ks++) {
        bf16x8 bk = *(const bf16x8*)&wfr[((8 + (ct << 1) + ks) * 64 + l) * 8];
        ak[ct] = __builtin_amdgcn_mfma_f32_16x16x32_bf16(af[ks], bk, ak[ct], 0, 0, 0);
      }
#pragma unroll
    for (int ct = 0; ct < 4; ct++)
#pragma unroll
      for (int ks = 0; ks < 2; ks++) {
        bf16x8 bv = *(const bf16x8*)&wfr[((16 + (ct << 1) + ks) * 64 + l) * 8];
        av[ct] = __builtin_amdgcn_mfma_f32_16x16x32_bf16(af[ks], bv, av[ct], 0, 0, 0);
      }
#pragma unroll
    for (int ct = 0; ct < 4; ct++) {
#pragma unroll
      for (int rr = 0; rr < 4; rr++) {
        qld[(orow + rr) * 72 + (ct << 4) + fr] = f2b(aq[ct][rr]);
        kld[(orow + rr) * 72 + (ct << 4) + fr] = f2b(ak[ct][rr]);
      }
      u16x4 vp;
      vp.x = f2b(av[ct][0]);
      vp.y = f2b(av[ct][1]);
      vp.z = f2b(av[ct][2]);
      vp.w = f2b(av[ct][3]);
      *(u16x4*)&vtl[((ct << 4) + fr) * 72 + orow] = vp;
    }
  }
  __syncthreads();

  {
    bf16x8 aq[2];
#pragma unroll
    for (int ks = 0; ks < 2; ks++)
      aq[ks] = *(const bf16x8*)&qld[((w << 4) + fr) * 72 + (ks << 5) + (fq << 3)];
    f32x4 accs[4];
#pragma unroll
    for (int nt = 0; nt < 4; nt++) accs[nt] = (f32x4){0.f, 0.f, 0.f, 0.f};
#pragma unroll
    for (int nt = 0; nt < 4; nt++)
#pragma unroll
      for (int ks = 0; ks < 2; ks++) {
        bf16x8 bk = *(const bf16x8*)&kld[((nt << 4) + fr) * 72 + (ks << 5) + (fq << 3)];
        accs[nt] = __builtin_amdgcn_mfma_f32_16x16x32_bf16(aq[ks], bk, accs[nt], 0, 0, 0);
      }
#pragma unroll
    for (int rr = 0; rr < 4; rr++) {
      float v0 = accs[0][rr] * 0.125f, v1 = accs[1][rr] * 0.125f;
      float v2 = accs[2][rr] * 0.125f, v3 = accs[3][rr] * 0.125f;
      float mx = fmaxf(fmaxf(v0, v1), fmaxf(v2, v3));
      mx = fmaxf(mx, __shfl_xor(mx, 1));
      mx = fmaxf(mx, __shfl_xor(mx, 2));
      mx = fmaxf(mx, __shfl_xor(mx, 4));
      mx = fmaxf(mx, __shfl_xor(mx, 8));
      float e0 = expf(v0 - mx), e1 = expf(v1 - mx);
      float e2 = expf(v2 - mx), e3 = expf(v3 - mx);
      float ss = e0 + e1 + e2 + e3;
      ss += __shfl_xor(ss, 1);
      ss += __shfl_xor(ss, 2);
      ss += __shfl_xor(ss, 4);
      ss += __shfl_xor(ss, 8);
      float inv = 1.0f / ss;
      stb[(orow + rr) * 72 + 0 * 16 + fr] = f2b(e0 * inv);
      stb[(orow + rr) * 72 + 1 * 16 + fr] = f2b(e1 * inv);
      stb[(orow + rr) * 72 + 2 * 16 + fr] = f2b(e2 * inv);
      stb[(orow + rr) * 72 + 3 * 16 + fr] = f2b(e3 * inv);
    }
  }
  __syncthreads();

  float o16[4][4];
  {
    bf16x8 ap[2];
#pragma unroll
    for (int ks = 0; ks < 2; ks++)
      ap[ks] = *(const bf16x8*)&stb[((w << 4) + fr) * 72 + (ks << 5) + (fq << 3)];
    f32x4 acco[4];
#pragma unroll
    for (int ct = 0; ct < 4; ct++) acco[ct] = (f32x4){0.f, 0.f, 0.f, 0.f};
#pragma unroll
    for (int ct = 0; ct < 4; ct++)
#pragma unroll
      for (int ks = 0; ks < 2; ks++) {
        bf16x8 bv = *(const bf16x8*)&vtl[((ct << 4) + fr) * 72 + (ks << 5) + (fq << 3)];
        acco[ct] = __builtin_amdgcn_mfma_f32_16x16x32_bf16(ap[ks], bv, acco[ct], 0, 0, 0);
      }
    float tgv[4], tbv[4];
#pragma unroll
    for (int ct = 0; ct < 4; ct++) {
      tgv[ct] = tg[(ct << 4) + fr];
      tbv[ct] = tb[(ct << 4) + fr];
    }
#pragma unroll
    for (int ct = 0; ct < 4; ct++)
#pragma unroll
      for (int rr = 0; rr < 4; rr++)
        o16[ct][rr] = acco[ct][rr] + st32[(orow + rr) * 68 + (ct << 4) + fr];
#pragma unroll
    for (int rr = 0; rr < 4; rr++) {
      float sm = o16[0][rr] + o16[1][rr] + o16[2][rr] + o16[3][rr];
      float sq = o16[0][rr] * o16[0][rr] + o16[1][rr] * o16[1][rr] +
                 o16[2][rr] * o16[2][rr] + o16[3][rr] * o16[3][rr];
      sm += __shfl_xor(sm, 1);
      sm += __shfl_xor(sm, 2);
      sm += __shfl_xor(sm, 4);
      sm += __shfl_xor(sm, 8);
      sq += __shfl_xor(sq, 1);
      sq += __shfl_xor(sq, 2);
      sq += __shfl_xor(sq, 4);
      sq += __shfl_xor(sq, 8);
      float mean = sm * (1.0f / 64.0f);
      float var = sq * (1.0f / 64.0f) - mean * mean;
      float rstd = rsqrtf(var + 1e-5f);
#pragma unroll
      for (int ct = 0; ct < 4; ct++) {
        float hv = (o16[ct][rr] - mean) * rstd * tgv[ct] + tbv[ct];
        qld[(orow + rr) * 72 + (ct << 4) + fr] = f2b(hv);
      }
    }
  }
  __syncthreads();

  {
    bf16x8 ah[2];
#pragma unroll
    for (int ks = 0; ks < 2; ks++)
      ah[ks] = *(const bf16x8*)&qld[((w << 4) + fr) * 72 + (ks << 5) + (fq << 3)];
    f32x4 accm[8];
#pragma unroll
    for (int et = 0; et < 8; et++) accm[et] = (f32x4){0.f, 0.f, 0.f, 0.f};
#pragma unroll
    for (int et = 0; et < 8; et++)
#pragma unroll
      for (int ks = 0; ks < 2; ks++) {
        bf16x8 bm = *(const bf16x8*)&wfr[((24 + (et << 1) + ks) * 64 + l) * 8];
        accm[et] = __builtin_amdgcn_mfma_f32_16x16x32_bf16(ah[ks], bm, accm[et], 0, 0, 0);
      }
#pragma unroll
    for (int et = 0; et < 8; et++) {
      float bv = bm1[(et << 4) + fr];
#pragma unroll
      for (int rr = 0; rr < 4; rr++) {
        float x = accm[et][rr] + bv;
        hmld[(orow + rr) * 136 + (et << 4) + fr] = f2b(gelu_exact(x));
      }
    }
  }
  __syncthreads();

  {
    bf16x8 ahm[4];
#pragma unroll
    for (int ks = 0; ks < 4; ks++)
      ahm[ks] = *(const bf16x8*)&hmld[((w << 4) + fr) * 136 + (ks << 5) + (fq << 3)];
    f32x4 acc2[4];
#pragma unroll
    for (int ct = 0; ct < 4; ct++) acc2[ct] = (f32x4){0.f, 0.f, 0.f, 0.f};
#pragma unroll
    for (int ct = 0; ct < 4; ct++)
#pragma unroll
      for (int ks = 0; ks < 4; ks++) {
        bf16x8 bw = *(const bf16x8*)&wfr[((40 + (ct << 2) + ks) * 64 + l) * 8];
        acc2[ct] = __builtin_amdgcn_mfma_f32_16x16x32_bf16(ahm[ks], bw, acc2[ct], 0, 0, 0);
      }
    float* tout = tokens + ((size_t)bh << 12);
#pragma unroll
    for (int ct = 0; ct < 4; ct++) {
      float bv = bm2[(ct << 4) + fr];
#pragma unroll
      for (int rr = 0; rr < 4; rr++)
        tout[(orow + rr) * 64 + (ct << 4) + fr] = acc2[ct][rr] + bv + o16[ct][rr];
    }
  }
}

// ---------------------------------------------------------------------------
// K8: deslice via MFMA, zero LDS. D[d][n] = tokens^T . sw^T per (b,h).
// Grid 512 = bh(32) x chunk(16); wave owns 128 n-rows (8 n-tiles).
// A-frags (tokens^T) resident from wtokf; B-frag = 16B contiguous sw row read;
// store u16x4 (4 consecutive d) per lane.
// ---------------------------------------------------------------------------
__global__ __launch_bounds__(256) void deslice_mfma(
    const unsigned short* __restrict__ wtokf, const unsigned short* __restrict__ sw,
    unsigned short* __restrict__ outx) {
  int bid = blockIdx.x;
  int bh = bid >> 4, c = bid & 15;
  int b = bh >> 3, h = bh & 7;
  int t = threadIdx.x, w = t >> 6, l = t & 63;
  const int fr = l & 15, fq = l >> 4;

  bf16x8 ta[4][2];
  const unsigned short* fp = wtokf + ((size_t)bh << 12);
#pragma unroll
  for (int mt = 0; mt < 4; mt++)
#pragma unroll
    for (int ks = 0; ks < 2; ks++)
      ta[mt][ks] = *(const bf16x8*)(fp + (((mt << 1) + ks) << 9) + (l << 3));

  int n0 = (c << 9) + (w << 7);
#pragma unroll 2
  for (int ntile = 0; ntile < 8; ntile++) {
    int nb = n0 + (ntile << 4);
    size_t rowb = ((size_t)(b * N_ + nb + fr) * 8 + h) << 6;
    bf16x8 b0 = *(const bf16x8*)(sw + rowb + (fq << 3));
    bf16x8 b1 = *(const bf16x8*)(sw + rowb + 32 + (fq << 3));
    f32x4 acc[4];
#pragma unroll
    for (int mt = 0; mt < 4; mt++) acc[mt] = (f32x4){0.f, 0.f, 0.f, 0.f};
#pragma unroll
    for (int mt = 0; mt < 4; mt++) {
      acc[mt] = __builtin_amdgcn_mfma_f32_16x16x32_bf16(ta[mt][0], b0, acc[mt], 0, 0, 0);
      acc[mt] = __builtin_amdgcn_mfma_f32_16x16x32_bf16(ta[mt][1], b1, acc[mt], 0, 0, 0);
    }
    unsigned short* op = outx + rowb + (fq << 2);
#pragma unroll
    for (int mt = 0; mt < 4; mt++) {
      u16x4 pk;
      pk.x = f2b(acc[mt][0]);
      pk.y = f2b(acc[mt][1]);
      pk.z = f2b(acc[mt][2]);
      pk.w = f2b(acc[mt][3]);
      *(u16x4*)(op + (mt << 4)) = pk;
    }
  }
}

// ---------------------------------------------------------------------------
extern "C" void kernel_launch(void* const* d_in, const int* in_sizes, int n_in,
                              void* d_out, int out_size, void* d_ws,
                              size_t ws_size, hipStream_t stream) {
  const float* fx = (const float*)d_in[0];
  const float* ln1g = (const float*)d_in[1];
  const float* ln1b = (const float*)d_in[2];
  const float* Wx = (const float*)d_in[3];
  const float* bx = (const float*)d_in[4];
  const float* Wfx = (const float*)d_in[5];
  const float* bfx = (const float*)d_in[6];
  const float* Wsl = (const float*)d_in[7];
  const float* bsl = (const float*)d_in[8];
  const float* temp = (const float*)d_in[9];
  const float* Wq = (const float*)d_in[10];
  const float* Wk = (const float*)d_in[11];
  const float* Wv = (const float*)d_in[12];
  const float* Wout = (const float*)d_in[13];
  const float* bout = (const float*)d_in[14];
  const float* tlng = (const float*)d_in[15];
  const float* tlnb = (const float*)d_in[16];
  const float* Wm1 = (const float*)d_in[17];
  const float* bm1 = (const float*)d_in[18];
  const float* Wm2 = (const float*)d_in[19];
  const float* bm2 = (const float*)d_in[20];
  float* out = (float*)d_out;

  char* p = (char*)d_ws;
  const size_t MC2 = (size_t)M_ * 512 * 2;
  unsigned short* fxn = (unsigned short*)p;  p += MC2;
  unsigned short* buf1 = (unsigned short*)p; p += MC2;  // x_mid -> slice_w
  unsigned short* bufT = (unsigned short*)p; p += MC2;  // fxT -> out_x
  unsigned short* WtX = (unsigned short*)p;  p += 512 * 512 * 2;
  unsigned short* WtF = (unsigned short*)p;  p += 512 * 512 * 2;
  unsigned short* WtO = (unsigned short*)p;  p += 512 * 512 * 2;
  unsigned short* wsf = (unsigned short*)p;  p += 8192;
  unsigned short* wfr = (unsigned short*)p;  p += 56 * 512 * 2;
  unsigned short* wtokf = (unsigned short*)p; p += (size_t)32 * 8 * 512 * 2;
  float* tok_part = (float*)p;  p += (size_t)512 * 4096 * 4;
  float* norm_part = (float*)p; p += (size_t)512 * 64 * 4;
  float* tokens = (float*)p;    p += (size_t)32 * 4096 * 4;
  float* stG = (float*)p;       p += (size_t)32 * 4096 * 4;

  ln_bf16<<<M_ / 4, 256, 0, stream>>>(fx, ln1g, ln1b, fxn);
  dim3 wg(8, 8);
  wconv_t<<<wg, 256, 0, stream>>>(Wx, WtX);
  wconv_t<<<wg, 256, 0, stream>>>(Wfx, WtF);
  wconv_t<<<wg, 256, 0, stream>>>(Wout, WtO);
  wslice_prep<<<1, 256, 0, stream>>>(Wsl, wsf);
  wfrag_prep<<<1, 256, 0, stream>>>(Wq, Wk, Wv, Wm1, Wm2, wfr);
  gemm_bf16<0, false, true, false><<<1024, 256, 0, stream>>>(fxn, WtX, bx, nullptr, buf1, 512);
  gemm_bf16<1, true, true, false><<<1024, 256, 0, stream>>>(WtF, fxn, bfx, nullptr, bufT, 32768);
  slice_mfma<<<4096, 256, 0, stream>>>(buf1, wsf, bsl, temp);
  pool_mfma<<<512, 256, 0, stream>>>(buf1, bufT, tok_part, norm_part);
  tok_reduce<<<128, 256, 0, stream>>>(tok_part, norm_part, stG);
  token_mfma<<<32, 256, 0, stream>>>(stG, wfr, tlng, tlnb, bm1, bm2, tokens);
  tokfrag_prep<<<32, 256, 0, stream>>>(tokens, wtokf);
  deslice_mfma<<<512, 256, 0, stream>>>(wtokf, buf1, bufT);
  gemm_bf16<0, false, false, true><<<1024, 256, 0, stream>>>(bufT, WtO, bout, fxn, out, 512);
}